// Round 14
// baseline (66.070 us; speedup 1.0000x reference)
//
#include <hip/hip_runtime.h>

// MSMLTransformerLayer — 4 launches. Stages 1-2 rebuilt as FULL-K-RESIDENT
// single-barrier kernels (64x64 tile, both operands fully in LDS, all loads
// issued before one barrier, then 32 MFMA/wave with no further barriers).
// kv_mfma/attlin byte-identical to R11 (best, 56.7). Casts in stage-1.

#define DIM 256
#define NTOK 4096

typedef __attribute__((ext_vector_type(8))) short short8;
typedef __attribute__((ext_vector_type(4))) short short4v;
typedef __attribute__((ext_vector_type(4))) float f32x4;

__device__ __forceinline__ float silu_f(float z) { return z / (1.f + __expf(-z)); }
__device__ __forceinline__ float elu2_f(float z) { return z > 0.f ? z + 2.f : __expf(z) + 1.f; }

__device__ __forceinline__ short f2bf(float f) {
    union { float f; unsigned u; } v; v.f = f;
    unsigned r = v.u + 0x7fffu + ((v.u >> 16) & 1u);
    return (short)(r >> 16);
}
__device__ __forceinline__ float bf2f(short s) {
    union { unsigned u; float f; } v; v.u = ((unsigned)(unsigned short)s) << 16;
    return v.f;
}
__device__ __forceinline__ short8 cvt8(const float* src) {
    const float4 a = *(const float4*)src;
    const float4 c = *(const float4*)(src + 4);
    short8 s;
    s[0] = f2bf(a.x); s[1] = f2bf(a.y); s[2] = f2bf(a.z); s[3] = f2bf(a.w);
    s[4] = f2bf(c.x); s[5] = f2bf(c.y); s[6] = f2bf(c.z); s[7] = f2bf(c.w);
    return s;
}
__device__ __forceinline__ void cast_chunk(const float* __restrict__ src, short* __restrict__ dst,
                                           int chunk, int tid) {
    const int base = chunk * 8192 + tid * 32;
    #pragma unroll
    for (int j = 0; j < 4; ++j)
        *(short8*)(dst + base + j * 8) = cvt8(src + base + j * 8);
}

#define LDW 264  // LDS row stride in shorts (528 B -> same bank profile as proven 72)

// ---------------- S1: full-K dual GEMM (silu) + weight-cast side-blocks ------
// grid (152,4,2): x<128 GEMM tiles 64 rows; x in [128,152) casts (y==0,z==0).
// z=0: act = silu(x@Wa^T+ba); z=1: h = silu(LN(x)@Wc^T+bc), LN in-kernel.
// Both operands staged FULL-K in LDS, one barrier, 8 kc of MFMA, no more syncs.
__global__ __launch_bounds__(256) void dual_fk(
        const float* __restrict__ XF,
        const float* __restrict__ W0f, const float* __restrict__ b0, short* __restrict__ Y0,
        const float* __restrict__ W1f, const float* __restrict__ b1, short* __restrict__ Y1,
        const float* __restrict__ G, const float* __restrict__ Bt,
        const float* __restrict__ Wkf, short* __restrict__ WKB,
        const float* __restrict__ Wqf, short* __restrict__ WQB,
        const float* __restrict__ Wlf, short* __restrict__ WLB) {
    const int tid = threadIdx.x;
    if (blockIdx.x >= 128) {
        if (blockIdx.y == 0 && blockIdx.z == 0) {
            const int which = blockIdx.x - 128;
            if (which < 8) cast_chunk(Wkf, WKB, which, tid);
            else if (which < 16) cast_chunk(Wqf, WQB, which - 8, tid);
            else cast_chunk(Wlf, WLB, which - 16, tid);
        }
        return;
    }
    __shared__ __align__(16) short Xs[64 * LDW];
    __shared__ __align__(16) short Ws[64 * LDW];
    __shared__ float stats[64][2];
    const int zz = blockIdx.z;
    const float* Wf = zz ? W1f : W0f;
    const float* bias = zz ? b1 : b0;
    short* Y = zz ? Y1 : Y0;
    const int r0 = blockIdx.x * 64, c0 = blockIdx.y * 64;
    const int wv = tid >> 6, l = tid & 63;
    const int lr = l & 15, lk = l >> 4;
    const int wm = (wv >> 1) * 32, wn = (wv & 1) * 32;
    const int srow = tid >> 2, scol = (tid & 3) * 64;

    if (zz) {  // LN stats: 4 threads/row, 64 elems each (proven R9 pattern)
        const float* src = XF + (size_t)(r0 + srow) * DIM + scol;
        float a1 = 0.f, a2 = 0.f;
        #pragma unroll
        for (int j = 0; j < 16; ++j) {
            const float4 v = *(const float4*)(src + j * 4);
            a1 += v.x + v.y + v.z + v.w;
            a2 += v.x * v.x + v.y * v.y + v.z * v.z + v.w * v.w;
        }
        a1 += __shfl_xor(a1, 1); a2 += __shfl_xor(a2, 1);
        a1 += __shfl_xor(a1, 2); a2 += __shfl_xor(a2, 2);
        if ((tid & 3) == 0) {
            const float mm = a1 * (1.f / DIM);
            stats[srow][0] = mm;
            stats[srow][1] = rsqrtf(a2 * (1.f / DIM) - mm * mm + 1e-5f);
        }
        __syncthreads();
    }

    // stage X full-K (f32 -> bf16, LN applied for z=1)
    if (zz) {
        const float mm = stats[srow][0], rs = stats[srow][1];
        #pragma unroll
        for (int j = 0; j < 8; ++j) {
            const float* src = XF + (size_t)(r0 + srow) * DIM + scol + j * 8;
            const float4 a = *(const float4*)src;
            const float4 c = *(const float4*)(src + 4);
            const float4 g1 = *(const float4*)(G + scol + j * 8);
            const float4 g2 = *(const float4*)(G + scol + j * 8 + 4);
            const float4 t1 = *(const float4*)(Bt + scol + j * 8);
            const float4 t2 = *(const float4*)(Bt + scol + j * 8 + 4);
            short8 s;
            s[0] = f2bf((a.x - mm) * rs * g1.x + t1.x);
            s[1] = f2bf((a.y - mm) * rs * g1.y + t1.y);
            s[2] = f2bf((a.z - mm) * rs * g1.z + t1.z);
            s[3] = f2bf((a.w - mm) * rs * g1.w + t1.w);
            s[4] = f2bf((c.x - mm) * rs * g2.x + t2.x);
            s[5] = f2bf((c.y - mm) * rs * g2.y + t2.y);
            s[6] = f2bf((c.z - mm) * rs * g2.z + t2.z);
            s[7] = f2bf((c.w - mm) * rs * g2.w + t2.w);
            *(short8*)&Xs[srow * LDW + scol + j * 8] = s;
        }
    } else {
        #pragma unroll
        for (int j = 0; j < 8; ++j)
            *(short8*)&Xs[srow * LDW + scol + j * 8] =
                cvt8(XF + (size_t)(r0 + srow) * DIM + scol + j * 8);
    }
    // stage W full-K
    #pragma unroll
    for (int j = 0; j < 8; ++j)
        *(short8*)&Ws[srow * LDW + scol + j * 8] =
            cvt8(Wf + (size_t)(c0 + srow) * DIM + scol + j * 8);
    __syncthreads();

    f32x4 acc[2][2];
    #pragma unroll
    for (int i = 0; i < 2; ++i)
        #pragma unroll
        for (int j = 0; j < 2; ++j) acc[i][j] = (f32x4){0.f, 0.f, 0.f, 0.f};
    #pragma unroll
    for (int kc = 0; kc < 8; ++kc) {
        short8 af[2], bfr[2];
        #pragma unroll
        for (int mi = 0; mi < 2; ++mi)
            af[mi] = *(const short8*)&Xs[(wm + mi * 16 + lr) * LDW + kc * 32 + lk * 8];
        #pragma unroll
        for (int ni = 0; ni < 2; ++ni)
            bfr[ni] = *(const short8*)&Ws[(wn + ni * 16 + lr) * LDW + kc * 32 + lk * 8];
        #pragma unroll
        for (int mi = 0; mi < 2; ++mi)
            #pragma unroll
            for (int ni = 0; ni < 2; ++ni)
                acc[mi][ni] = __builtin_amdgcn_mfma_f32_16x16x32_bf16(af[mi], bfr[ni], acc[mi][ni], 0, 0, 0);
    }
    #pragma unroll
    for (int mi = 0; mi < 2; ++mi)
        #pragma unroll
        for (int ni = 0; ni < 2; ++ni) {
            const int c = c0 + wn + ni * 16 + lr;
            const float bv = bias[c];
            #pragma unroll
            for (int i = 0; i < 4; ++i) {
                const int r = r0 + wm + mi * 16 + lk * 4 + i;
                Y[(size_t)r * DIM + c] = f2bf(silu_f(acc[mi][ni][i] + bv));
            }
        }
}

// ---------------- S2: full-K k/q GEMM (elu+2) --------------------------------
// grid (136,4): bx<128 phik tile bx; bx in [128,136) phiq (remapped rows).
__global__ __launch_bounds__(256) void kq_fk(
        const short* __restrict__ H, const short* __restrict__ WKB, const float* __restrict__ bk, short* __restrict__ PK,
        const short* __restrict__ WQB, const float* __restrict__ bq, short* __restrict__ PQ) {
    __shared__ __align__(16) short Xs[64 * LDW];
    __shared__ __align__(16) short Ws[64 * LDW];
    const int bx = blockIdx.x;
    const bool isq = bx >= 128;
    const short* W = isq ? WQB : WKB;
    const float* bias = isq ? bq : bk;
    short* Y = isq ? PQ : PK;
    const int r0 = (isq ? bx - 128 : bx) * 64;
    const int c0 = blockIdx.y * 64;
    const int tid = threadIdx.x;
    const int wv = tid >> 6, l = tid & 63;
    const int lr = l & 15, lk = l >> 4;
    const int wm = (wv >> 1) * 32, wn = (wv & 1) * 32;
    const int srow = tid >> 2, scol = (tid & 3) * 64;

    {
        int grow = r0 + srow;
        if (isq) grow = ((grow >> 8) << 12) + (grow & 255);
        #pragma unroll
        for (int j = 0; j < 8; ++j)
            *(short8*)&Xs[srow * LDW + scol + j * 8] =
                *(const short8*)(H + (size_t)grow * DIM + scol + j * 8);
        #pragma unroll
        for (int j = 0; j < 8; ++j)
            *(short8*)&Ws[srow * LDW + scol + j * 8] =
                *(const short8*)(W + (size_t)(c0 + srow) * DIM + scol + j * 8);
    }
    __syncthreads();

    f32x4 acc[2][2];
    #pragma unroll
    for (int i = 0; i < 2; ++i)
        #pragma unroll
        for (int j = 0; j < 2; ++j) acc[i][j] = (f32x4){0.f, 0.f, 0.f, 0.f};
    #pragma unroll
    for (int kc = 0; kc < 8; ++kc) {
        short8 af[2], bfr[2];
        #pragma unroll
        for (int mi = 0; mi < 2; ++mi)
            af[mi] = *(const short8*)&Xs[(wm + mi * 16 + lr) * LDW + kc * 32 + lk * 8];
        #pragma unroll
        for (int ni = 0; ni < 2; ++ni)
            bfr[ni] = *(const short8*)&Ws[(wn + ni * 16 + lr) * LDW + kc * 32 + lk * 8];
        #pragma unroll
        for (int mi = 0; mi < 2; ++mi)
            #pragma unroll
            for (int ni = 0; ni < 2; ++ni)
                acc[mi][ni] = __builtin_amdgcn_mfma_f32_16x16x32_bf16(af[mi], bfr[ni], acc[mi][ni], 0, 0, 0);
    }
    #pragma unroll
    for (int mi = 0; mi < 2; ++mi)
        #pragma unroll
        for (int ni = 0; ni < 2; ++ni) {
            const int c = c0 + wn + ni * 16 + lr;
            const float bv = bias[c];
            #pragma unroll
            for (int i = 0; i < 4; ++i) {
                const int r = r0 + wm + mi * 16 + lk * 4 + i;
                Y[(size_t)r * DIM + c] = f2bf(elu2_f(acc[mi][ni][i] + bv));
            }
        }
}

// ---------------- KV (R11-proven, casts removed) -----------------------------
__global__ __launch_bounds__(256) void kv_mfma(const short* __restrict__ HB, const short* __restrict__ PK,
                                               short* __restrict__ KVT) {
    __shared__ __align__(16) short Hs[64 * 68];
    __shared__ __align__(16) short Ps[64 * 68];
    const int tid = threadIdx.x;
    const int bm = blockIdx.x, b = bm >> 4, m = bm & 15;
    const int d0 = blockIdx.y * 64, c0 = blockIdx.z * 64;
    const int wv = tid >> 6, l = tid & 63;
    const int lr = l & 15, lk = l >> 4;
    const int wd = (wv >> 1) * 32, wc = (wv & 1) * 32;
    f32x4 acc[2][2];
    #pragma unroll
    for (int i = 0; i < 2; ++i)
        #pragma unroll
        for (int j = 0; j < 2; ++j) acc[i][j] = (f32x4){0.f, 0.f, 0.f, 0.f};
    const size_t hbase = (size_t)b * NTOK * DIM;
    const int sr = tid >> 3, sc = (tid & 7) * 8;
    for (int kt = 0; kt < 256; kt += 64) {
        #pragma unroll
        for (int pp = 0; pp < 2; ++pp) {
            const int w = sr + pp * 32;
            const size_t gg = hbase + (size_t)((kt + w) * 16 + m) * DIM;
            short8 hv = *(const short8*)(HB + gg + d0 + sc);
            short8 pv = *(const short8*)(PK + gg + c0 + sc);
            *(short4v*)&Hs[w * 68 + sc]     = __builtin_shufflevector(hv, hv, 0, 1, 2, 3);
            *(short4v*)&Hs[w * 68 + sc + 4] = __builtin_shufflevector(hv, hv, 4, 5, 6, 7);
            *(short4v*)&Ps[w * 68 + sc]     = __builtin_shufflevector(pv, pv, 0, 1, 2, 3);
            *(short4v*)&Ps[w * 68 + sc + 4] = __builtin_shufflevector(pv, pv, 4, 5, 6, 7);
        }
        __syncthreads();
        #pragma unroll
        for (int kc = 0; kc < 2; ++kc) {
            const int kb = kc * 32 + lk * 8;
            short8 af[2], bfr[2];
            #pragma unroll
            for (int di = 0; di < 2; ++di)
                #pragma unroll
                for (int i = 0; i < 8; ++i)
                    af[di][i] = Hs[(kb + i) * 68 + wd + di * 16 + lr];
            #pragma unroll
            for (int ci = 0; ci < 2; ++ci)
                #pragma unroll
                for (int i = 0; i < 8; ++i)
                    bfr[ci][i] = Ps[(kb + i) * 68 + wc + ci * 16 + lr];
            #pragma unroll
            for (int di = 0; di < 2; ++di)
                #pragma unroll
                for (int ci = 0; ci < 2; ++ci)
                    acc[di][ci] = __builtin_amdgcn_mfma_f32_16x16x32_bf16(af[di], bfr[ci], acc[di][ci], 0, 0, 0);
        }
        __syncthreads();
    }
    #pragma unroll
    for (int di = 0; di < 2; ++di)
        #pragma unroll
        for (int ci = 0; ci < 2; ++ci)
            #pragma unroll
            for (int i = 0; i < 4; ++i) {
                const int d = d0 + wd + di * 16 + lk * 4 + i;
                const int c = c0 + wc + ci * 16 + lr;
                KVT[((size_t)bm * DIM + d) * DIM + c] = f2bf(acc[di][ci][i]);
            }
}

// ---------------- attlin (R11-proven, bf16 Wl) -------------------------------
__global__ __launch_bounds__(256) void attlin(
        const short* __restrict__ PQ, const short* __restrict__ KVT,
        const float* __restrict__ emb, const float* __restrict__ pw, const float* __restrict__ pb,
        const short* __restrict__ AR,
        const short* __restrict__ WLB, const float* __restrict__ bl,
        const short* __restrict__ HB, const float* __restrict__ G, const float* __restrict__ Bt,
        float* __restrict__ Y) {
    __shared__ __align__(16) short Qs[32 * 264];
    __shared__ __align__(16) short AGs[32 * 264];
    __shared__ __align__(16) short Bs[256 * 72];
    __shared__ float s1buf[32][2];
    __shared__ float s2buf[32][2];
    const int tid = threadIdx.x;
    const int wv = tid >> 6, l = tid & 63;
    const int lr = l & 15, lk = l >> 4;
    const int bm = blockIdx.x, b = bm >> 4, m = bm & 15;
    const int q0 = blockIdx.y * 32;
    const int wq = (wv >> 1) * 16;
    const int wd = (wv & 1) * 32;
    const int sr = tid >> 3, sc = (tid & 7) * 8;

    #pragma unroll
    for (int pp = 0; pp < 4; ++pp) {
        const int chunk = tid + pp * 256;
        const int row = chunk >> 5, cc = (chunk & 31) * 8;
        *(short8*)&Qs[row * 264 + cc] = *(const short8*)(PQ + (size_t)(b * 256 + q0 + row) * DIM + cc);
    }

    f32x4 accA[4][2];
    #pragma unroll
    for (int i = 0; i < 4; ++i)
        #pragma unroll
        for (int j = 0; j < 2; ++j) accA[i][j] = (f32x4){0.f, 0.f, 0.f, 0.f};
    for (int kt = 0; kt < DIM; kt += 64) {
        #pragma unroll
        for (int pp = 0; pp < 8; ++pp) {
            const int row = sr + pp * 32;
            *(short8*)&Bs[row * 72 + sc] = *(const short8*)(KVT + ((size_t)bm * DIM + row) * DIM + kt + sc);
        }
        __syncthreads();
        #pragma unroll
        for (int kc = 0; kc < 2; ++kc) {
            const short8 af = *(const short8*)&Qs[(wq + lr) * 264 + kt + kc * 32 + lk * 8];
            #pragma unroll
            for (int dc = 0; dc < 4; ++dc)
                #pragma unroll
                for (int ni = 0; ni < 2; ++ni) {
                    const short8 bfr = *(const short8*)&Bs[(dc * 64 + wd + ni * 16 + lr) * 72 + kc * 32 + lk * 8];
                    accA[dc][ni] = __builtin_amdgcn_mfma_f32_16x16x32_bf16(af, bfr, accA[dc][ni], 0, 0, 0);
                }
        }
        __syncthreads();
    }
    {
        const float pw0 = pw[0], pw1 = pw[1], pw2 = pw[2], pbv = pb[0];
        #pragma unroll
        for (int i = 0; i < 4; ++i) {
            const int rloc = wq + lk * 4 + i;
            const int qr = q0 + rloc;
            const int widx = qr >> 4, nidx = qr & 15;
            const float* e = emb + ((((size_t)(2 + b) * 256 + widx) * 16 + nidx) * 16 + m) * 3;
            const float pv = e[0] * pw0 + e[1] * pw1 + e[2] * pw2 + pbv;
            const int t = qr * 16 + m;
            #pragma unroll
            for (int dc = 0; dc < 4; ++dc)
                #pragma unroll
                for (int ni = 0; ni < 2; ++ni) {
                    const int d = dc * 64 + wd + ni * 16 + lr;
                    const size_t o = ((size_t)b * NTOK + t) * DIM + d;
                    AGs[rloc * 264 + d] = f2bf((accA[dc][ni][i] + pv) * bf2f(AR[o]));
                }
        }
    }
    __syncthreads();

    const int wn2 = (wv & 1) * 128;
    f32x4 accB[8];
    #pragma unroll
    for (int i = 0; i < 8; ++i) accB[i] = (f32x4){0.f, 0.f, 0.f, 0.f};
    for (int kt = 0; kt < DIM; kt += 64) {
        #pragma unroll
        for (int pp = 0; pp < 8; ++pp) {
            const int row = sr + pp * 32;
            *(short8*)&Bs[row * 72 + sc] = *(const short8*)(WLB + (size_t)row * DIM + kt + sc);
        }
        __syncthreads();
        #pragma unroll
        for (int kc = 0; kc < 2; ++kc) {
            const short8 af = *(const short8*)&AGs[(wq + lr) * 264 + kt + kc * 32 + lk * 8];
            #pragma unroll
            for (int ni = 0; ni < 8; ++ni) {
                const short8 bfr = *(const short8*)&Bs[(wn2 + ni * 16 + lr) * 72 + kc * 32 + lk * 8];
                accB[ni] = __builtin_amdgcn_mfma_f32_16x16x32_bf16(af, bfr, accB[ni], 0, 0, 0);
            }
        }
        __syncthreads();
    }
    float s1[4] = {0.f, 0.f, 0.f, 0.f}, s2[4] = {0.f, 0.f, 0.f, 0.f};
    #pragma unroll
    for (int ni = 0; ni < 8; ++ni) {
        const int col = wn2 + ni * 16 + lr;
        const float bv = bl[col];
        #pragma unroll
        for (int i = 0; i < 4; ++i) {
            const int rloc = wq + lk * 4 + i;
            const int t = (q0 + rloc) * 16 + m;
            const float z = accB[ni][i] + bv + bf2f(HB[((size_t)b * NTOK + t) * DIM + col]);
            accB[ni][i] = z;
            s1[i] += z; s2[i] += z * z;
        }
    }
    #pragma unroll
    for (int o = 1; o < 16; o <<= 1) {
        #pragma unroll
        for (int i = 0; i < 4; ++i) {
            s1[i] += __shfl_xor(s1[i], o);
            s2[i] += __shfl_xor(s2[i], o);
        }
    }
    if (lr == 0) {
        #pragma unroll
        for (int i = 0; i < 4; ++i) {
            const int rloc = wq + lk * 4 + i;
            s1buf[rloc][wv & 1] = s1[i];
            s2buf[rloc][wv & 1] = s2[i];
        }
    }
    __syncthreads();
    float mean[4], rstd[4];
    #pragma unroll
    for (int i = 0; i < 4; ++i) {
        const int rloc = wq + lk * 4 + i;
        const float t1 = s1buf[rloc][0] + s1buf[rloc][1];
        const float t2 = s2buf[rloc][0] + s2buf[rloc][1];
        const float mm = t1 * (1.f / DIM);
        mean[i] = mm;
        rstd[i] = rsqrtf(t2 * (1.f / DIM) - mm * mm + 1e-5f);
    }
    #pragma unroll
    for (int ni = 0; ni < 8; ++ni) {
        const int col = wn2 + ni * 16 + lr;
        const float gv = G[col], bv2 = Bt[col];
        #pragma unroll
        for (int i = 0; i < 4; ++i) {
            const int rloc = wq + lk * 4 + i;
            const int t = (q0 + rloc) * 16 + m;
            Y[((size_t)b * NTOK + t) * DIM + col] = (accB[ni][i] - mean[i]) * rstd[i] * gv + bv2;
        }
    }
}

extern "C" void kernel_launch(void* const* d_in, const int* in_sizes, int n_in,
                              void* d_out, int out_size, void* d_ws, size_t ws_size,
                              hipStream_t stream) {
    const float* x   = (const float*)d_in[0];
    const float* emb = (const float*)d_in[1];
    const float* Wa  = (const float*)d_in[2];
    const float* ba  = (const float*)d_in[3];
    const float* lng = (const float*)d_in[4];
    const float* lnb = (const float*)d_in[5];
    const float* Wc  = (const float*)d_in[6];
    const float* bc  = (const float*)d_in[7];
    const float* Wq  = (const float*)d_in[8];
    const float* bq  = (const float*)d_in[9];
    const float* Wk  = (const float*)d_in[10];
    const float* bk  = (const float*)d_in[11];
    const float* pw  = (const float*)d_in[12];
    const float* pb  = (const float*)d_in[13];
    const float* Wl  = (const float*)d_in[14];
    const float* bl  = (const float*)d_in[15];
    const float* ng  = (const float*)d_in[16];
    const float* nb  = (const float*)d_in[17];

    char* ws = (char*)d_ws;
    const size_t MB = 1024 * 1024;
    short* h_bf   = (short*)(ws + 0 * MB);    // 4 MB
    short* phik   = (short*)(ws + 4 * MB);    // 4 MB
    short* phiq   = (short*)(ws + 8 * MB);    // 256 KB
    short* kvT    = (short*)(ws + 9 * MB);    // 4 MB  [9,13)
    short* act_bf = (short*)(ws + 13 * MB);   // 4 MB  [13,17)
    short* Wk_bf  = (short*)(ws + 17 * MB);   // 128 KB
    short* Wq_bf  = (short*)(ws + 17 * MB + 128 * 1024);
    short* Wl_bf  = (short*)(ws + 17 * MB + 256 * 1024);

    dual_fk<<<dim3(152, 4, 2), dim3(256), 0, stream>>>(x, Wa, ba, act_bf,
                                                       Wc, bc, h_bf, lng, lnb,
                                                       Wk, Wk_bf, Wq, Wq_bf, Wl, Wl_bf);
    kq_fk<<<dim3(136, 4), dim3(256), 0, stream>>>(h_bf, Wk_bf, bk, phik, Wq_bf, bq, phiq);
    kv_mfma<<<dim3(32, 4, 4), dim3(256), 0, stream>>>(h_bf, phik, kvT);
    attlin<<<dim3(32, 8), dim3(256), 0, stream>>>(phiq, kvT, emb, pw, pb, act_bf, Wl_bf, bl,
                                                  h_bf, ng, nb, (float*)d_out);
}

// Round 15
// 56.525 us; speedup vs baseline: 1.1689x; 1.1689x over previous
//
#include <hip/hip_runtime.h>

// MSMLTransformerLayer — R11 revert (best known: 56.7 µs). 4 launches:
// fused_dual (act,h + Wk/Wq casts) -> gemm_kq (bf16 W) -> kv_mfma (+Wl cast)
// -> attlin (bf16 Wl). R12 coop=398µs, R13 recompute=58.7, R14 full-K=66.1
// all falsified; this structure is the proven optimum.

#define DIM 256
#define NTOK 4096

typedef __attribute__((ext_vector_type(8))) short short8;
typedef __attribute__((ext_vector_type(4))) short short4v;
typedef __attribute__((ext_vector_type(4))) float f32x4;

__device__ __forceinline__ float silu_f(float z) { return z / (1.f + __expf(-z)); }
__device__ __forceinline__ float elu2_f(float z) { return z > 0.f ? z + 2.f : __expf(z) + 1.f; }

__device__ __forceinline__ short f2bf(float f) {
    union { float f; unsigned u; } v; v.f = f;
    unsigned r = v.u + 0x7fffu + ((v.u >> 16) & 1u);
    return (short)(r >> 16);
}
__device__ __forceinline__ float bf2f(short s) {
    union { unsigned u; float f; } v; v.u = ((unsigned)(unsigned short)s) << 16;
    return v.f;
}
__device__ __forceinline__ short8 cvt8(const float* src) {
    const float4 a = *(const float4*)src;
    const float4 c = *(const float4*)(src + 4);
    short8 s;
    s[0] = f2bf(a.x); s[1] = f2bf(a.y); s[2] = f2bf(a.z); s[3] = f2bf(a.w);
    s[4] = f2bf(c.x); s[5] = f2bf(c.y); s[6] = f2bf(c.z); s[7] = f2bf(c.w);
    return s;
}

// 1/8th of a 256x256 f32->bf16 cast: chunk in [0,8), 256 threads x 32 elems.
__device__ __forceinline__ void cast_chunk(const float* __restrict__ src, short* __restrict__ dst,
                                           int chunk, int tid) {
    const int base = chunk * 8192 + tid * 32;
    #pragma unroll
    for (int j = 0; j < 4; ++j)
        *(short8*)(dst + base + j * 8) = cvt8(src + base + j * 8);
}

// ---------------- fused dual GEMM (silu) + Wk/Wq cast side-blocks ------------
// Block tile 128x64, grid (80,4,2): x<64 GEMM; x in [64,80) cast (y==0,z==0).
// z=0: act = silu(x@Wa^T+ba); z=1: h = silu(LN(x)@Wc^T+bc), LN in-kernel.
__global__ __launch_bounds__(256) void fused_dual(
        const float* __restrict__ XF,
        const float* __restrict__ W0f, const float* __restrict__ b0, short* __restrict__ Y0,
        const float* __restrict__ W1f, const float* __restrict__ b1, short* __restrict__ Y1,
        const float* __restrict__ G, const float* __restrict__ Bt,
        const float* __restrict__ Wkf, short* __restrict__ WKB,
        const float* __restrict__ Wqf, short* __restrict__ WQB) {
    const int tid = threadIdx.x;
    if (blockIdx.x >= 64) {
        if (blockIdx.y == 0 && blockIdx.z == 0) {
            const int which = blockIdx.x - 64;
            if (which < 8) cast_chunk(Wkf, WKB, which, tid);
            else cast_chunk(Wqf, WQB, which - 8, tid);
        }
        return;
    }
    __shared__ __align__(16) short Xs[128 * 72];
    __shared__ __align__(16) short Ws[64 * 72];
    __shared__ float stats[128][2];
    const int zz = blockIdx.z;
    const float* Wf = zz ? W1f : W0f;
    const float* bias = zz ? b1 : b0;
    short* Y = zz ? Y1 : Y0;
    const int wv = tid >> 6, l = tid & 63;
    const int lr = l & 15, lk = l >> 4;
    const int r0 = blockIdx.x * 128, c0 = blockIdx.y * 64;
    const int wm = (wv >> 1) * 64, wn = (wv & 1) * 32;

    if (zz) {  // pass 1: LN stats for rows r0..r0+127 (2 threads per row)
        const int prow = tid >> 1, phalf = tid & 1;
        const float* src = XF + (size_t)(r0 + prow) * DIM + phalf * 128;
        float a1 = 0.f, a2 = 0.f;
        #pragma unroll 8
        for (int j = 0; j < 32; ++j) {
            const float4 v = *(const float4*)(src + j * 4);
            a1 += v.x + v.y + v.z + v.w;
            a2 += v.x * v.x + v.y * v.y + v.z * v.z + v.w * v.w;
        }
        a1 += __shfl_xor(a1, 1);
        a2 += __shfl_xor(a2, 1);
        if (!phalf) {
            const float mm = a1 * (1.f / DIM);
            stats[prow][0] = mm;
            stats[prow][1] = rsqrtf(a2 * (1.f / DIM) - mm * mm + 1e-5f);
        }
        __syncthreads();
    }

    f32x4 acc[4][2];
    #pragma unroll
    for (int i = 0; i < 4; ++i)
        #pragma unroll
        for (int j = 0; j < 2; ++j) acc[i][j] = (f32x4){0.f, 0.f, 0.f, 0.f};
    const int sr = tid >> 3, sc = (tid & 7) * 8;
    for (int kt = 0; kt < DIM; kt += 64) {
        float gv[8], bv[8];
        if (zz) {
            const float4 g1 = *(const float4*)(G + kt + sc);
            const float4 g2 = *(const float4*)(G + kt + sc + 4);
            const float4 t1 = *(const float4*)(Bt + kt + sc);
            const float4 t2 = *(const float4*)(Bt + kt + sc + 4);
            gv[0] = g1.x; gv[1] = g1.y; gv[2] = g1.z; gv[3] = g1.w;
            gv[4] = g2.x; gv[5] = g2.y; gv[6] = g2.z; gv[7] = g2.w;
            bv[0] = t1.x; bv[1] = t1.y; bv[2] = t1.z; bv[3] = t1.w;
            bv[4] = t2.x; bv[5] = t2.y; bv[6] = t2.z; bv[7] = t2.w;
        }
        #pragma unroll
        for (int p = 0; p < 4; ++p) {
            const int row = sr + p * 32;
            const float* src = XF + (size_t)(r0 + row) * DIM + kt + sc;
            const float4 a = *(const float4*)src;
            const float4 c = *(const float4*)(src + 4);
            float v[8] = {a.x, a.y, a.z, a.w, c.x, c.y, c.z, c.w};
            short8 s;
            if (zz) {
                const float mm = stats[row][0], rs = stats[row][1];
                #pragma unroll
                for (int j = 0; j < 8; ++j) s[j] = f2bf((v[j] - mm) * rs * gv[j] + bv[j]);
            } else {
                #pragma unroll
                for (int j = 0; j < 8; ++j) s[j] = f2bf(v[j]);
            }
            *(short8*)&Xs[row * 72 + sc] = s;
        }
        #pragma unroll
        for (int p = 0; p < 2; ++p) {
            const int row = sr + p * 32;
            *(short8*)&Ws[row * 72 + sc] = cvt8(Wf + (size_t)(c0 + row) * DIM + kt + sc);
        }
        __syncthreads();
        #pragma unroll
        for (int kc = 0; kc < 2; ++kc) {
            short8 af[4], bfr[2];
            #pragma unroll
            for (int mi = 0; mi < 4; ++mi)
                af[mi] = *(const short8*)&Xs[(wm + mi * 16 + lr) * 72 + kc * 32 + lk * 8];
            #pragma unroll
            for (int ni = 0; ni < 2; ++ni)
                bfr[ni] = *(const short8*)&Ws[(wn + ni * 16 + lr) * 72 + kc * 32 + lk * 8];
            #pragma unroll
            for (int mi = 0; mi < 4; ++mi)
                #pragma unroll
                for (int ni = 0; ni < 2; ++ni)
                    acc[mi][ni] = __builtin_amdgcn_mfma_f32_16x16x32_bf16(af[mi], bfr[ni], acc[mi][ni], 0, 0, 0);
        }
        __syncthreads();
    }
    #pragma unroll
    for (int mi = 0; mi < 4; ++mi)
        #pragma unroll
        for (int ni = 0; ni < 2; ++ni) {
            const int c = c0 + wn + ni * 16 + lr;
            const float bv2 = bias[c];
            #pragma unroll
            for (int i = 0; i < 4; ++i) {
                const int r = r0 + wm + mi * 16 + lk * 4 + i;
                Y[(size_t)r * DIM + c] = f2bf(silu_f(acc[mi][ni][i] + bv2));
            }
        }
}

// ---------------- k/q GEMM (elu+2): bx<64 phik; bx>=64 phiq. bf16 weights. ---
__global__ __launch_bounds__(256) void gemm_kq(
        const short* __restrict__ H, const short* __restrict__ WKB, const float* __restrict__ bk, short* __restrict__ PK,
        const short* __restrict__ WQB, const float* __restrict__ bq, short* __restrict__ PQ) {
    __shared__ __align__(16) short Xs[128 * 72];
    __shared__ __align__(16) short Ws[64 * 72];
    const int bx = blockIdx.x;
    const bool isq = bx >= 64;
    const short* W = isq ? WQB : WKB;
    const float* bias = isq ? bq : bk;
    short* Y = isq ? PQ : PK;
    const int r0 = (isq ? bx - 64 : bx) * 128;
    const int c0 = blockIdx.y * 64;
    const int tid = threadIdx.x;
    const int wv = tid >> 6, l = tid & 63;
    const int lr = l & 15, lk = l >> 4;
    const int wm = (wv >> 1) * 64, wn = (wv & 1) * 32;
    f32x4 acc[4][2];
    #pragma unroll
    for (int i = 0; i < 4; ++i)
        #pragma unroll
        for (int j = 0; j < 2; ++j) acc[i][j] = (f32x4){0.f, 0.f, 0.f, 0.f};
    const int sr = tid >> 3, sc = (tid & 7) * 8;
    for (int kt = 0; kt < DIM; kt += 64) {
        #pragma unroll
        for (int p = 0; p < 4; ++p) {
            const int row = sr + p * 32;
            int grow = r0 + row;
            if (isq) grow = ((grow >> 8) << 12) + (grow & 255);
            *(short8*)&Xs[row * 72 + sc] = *(const short8*)(H + (size_t)grow * DIM + kt + sc);
        }
        #pragma unroll
        for (int p = 0; p < 2; ++p) {
            const int row = sr + p * 32;
            *(short8*)&Ws[row * 72 + sc] = *(const short8*)(W + (size_t)(c0 + row) * DIM + kt + sc);
        }
        __syncthreads();
        #pragma unroll
        for (int kc = 0; kc < 2; ++kc) {
            short8 af[4], bfr[2];
            #pragma unroll
            for (int mi = 0; mi < 4; ++mi)
                af[mi] = *(const short8*)&Xs[(wm + mi * 16 + lr) * 72 + kc * 32 + lk * 8];
            #pragma unroll
            for (int ni = 0; ni < 2; ++ni)
                bfr[ni] = *(const short8*)&Ws[(wn + ni * 16 + lr) * 72 + kc * 32 + lk * 8];
            #pragma unroll
            for (int mi = 0; mi < 4; ++mi)
                #pragma unroll
                for (int ni = 0; ni < 2; ++ni)
                    acc[mi][ni] = __builtin_amdgcn_mfma_f32_16x16x32_bf16(af[mi], bfr[ni], acc[mi][ni], 0, 0, 0);
        }
        __syncthreads();
    }
    #pragma unroll
    for (int mi = 0; mi < 4; ++mi)
        #pragma unroll
        for (int ni = 0; ni < 2; ++ni) {
            const int c = c0 + wn + ni * 16 + lr;
            const float bv = bias[c];
            #pragma unroll
            for (int i = 0; i < 4; ++i) {
                const int r = r0 + wm + mi * 16 + lk * 4 + i;
                Y[(size_t)r * DIM + c] = f2bf(elu2_f(acc[mi][ni][i] + bv));
            }
        }
}

// ---------------- KV + Wl cast side-blocks -----------------------------------
// grid (40,4,4): x<32 KV tiles; x in [32,40) cast Wl (y==0,z==0).
__global__ __launch_bounds__(256) void kv_mfma(const short* __restrict__ HB, const short* __restrict__ PK,
                                               short* __restrict__ KVT,
                                               const float* __restrict__ Wlf, short* __restrict__ WLB) {
    const int tid = threadIdx.x;
    if (blockIdx.x >= 32) {
        if (blockIdx.y == 0 && blockIdx.z == 0)
            cast_chunk(Wlf, WLB, blockIdx.x - 32, tid);
        return;
    }
    __shared__ __align__(16) short Hs[64 * 68];
    __shared__ __align__(16) short Ps[64 * 68];
    const int bm = blockIdx.x, b = bm >> 4, m = bm & 15;
    const int d0 = blockIdx.y * 64, c0 = blockIdx.z * 64;
    const int wv = tid >> 6, l = tid & 63;
    const int lr = l & 15, lk = l >> 4;
    const int wd = (wv >> 1) * 32, wc = (wv & 1) * 32;
    f32x4 acc[2][2];
    #pragma unroll
    for (int i = 0; i < 2; ++i)
        #pragma unroll
        for (int j = 0; j < 2; ++j) acc[i][j] = (f32x4){0.f, 0.f, 0.f, 0.f};
    const size_t hbase = (size_t)b * NTOK * DIM;
    const int sr = tid >> 3, sc = (tid & 7) * 8;
    for (int kt = 0; kt < 256; kt += 64) {
        #pragma unroll
        for (int p = 0; p < 2; ++p) {
            const int w = sr + p * 32;
            const size_t gg = hbase + (size_t)((kt + w) * 16 + m) * DIM;
            short8 hv = *(const short8*)(HB + gg + d0 + sc);
            short8 pv = *(const short8*)(PK + gg + c0 + sc);
            *(short4v*)&Hs[w * 68 + sc]     = __builtin_shufflevector(hv, hv, 0, 1, 2, 3);
            *(short4v*)&Hs[w * 68 + sc + 4] = __builtin_shufflevector(hv, hv, 4, 5, 6, 7);
            *(short4v*)&Ps[w * 68 + sc]     = __builtin_shufflevector(pv, pv, 0, 1, 2, 3);
            *(short4v*)&Ps[w * 68 + sc + 4] = __builtin_shufflevector(pv, pv, 4, 5, 6, 7);
        }
        __syncthreads();
        #pragma unroll
        for (int kc = 0; kc < 2; ++kc) {
            const int kb = kc * 32 + lk * 8;
            short8 af[2], bfr[2];
            #pragma unroll
            for (int di = 0; di < 2; ++di)
                #pragma unroll
                for (int i = 0; i < 8; ++i)
                    af[di][i] = Hs[(kb + i) * 68 + wd + di * 16 + lr];
            #pragma unroll
            for (int ci = 0; ci < 2; ++ci)
                #pragma unroll
                for (int i = 0; i < 8; ++i)
                    bfr[ci][i] = Ps[(kb + i) * 68 + wc + ci * 16 + lr];
            #pragma unroll
            for (int di = 0; di < 2; ++di)
                #pragma unroll
                for (int ci = 0; ci < 2; ++ci)
                    acc[di][ci] = __builtin_amdgcn_mfma_f32_16x16x32_bf16(af[di], bfr[ci], acc[di][ci], 0, 0, 0);
        }
        __syncthreads();
    }
    #pragma unroll
    for (int di = 0; di < 2; ++di)
        #pragma unroll
        for (int ci = 0; ci < 2; ++ci)
            #pragma unroll
            for (int i = 0; i < 4; ++i) {
                const int d = d0 + wd + di * 16 + lk * 4 + i;
                const int c = c0 + wc + ci * 16 + lr;
                KVT[((size_t)bm * DIM + d) * DIM + c] = f2bf(acc[di][ci][i]);
            }
}

// ---------------- attlin: bf16 Wl ---------------------------------------------
__global__ __launch_bounds__(256) void attlin(
        const short* __restrict__ PQ, const short* __restrict__ KVT,
        const float* __restrict__ emb, const float* __restrict__ pw, const float* __restrict__ pb,
        const short* __restrict__ AR,
        const short* __restrict__ WLB, const float* __restrict__ bl,
        const short* __restrict__ HB, const float* __restrict__ G, const float* __restrict__ Bt,
        float* __restrict__ Y) {
    __shared__ __align__(16) short Qs[32 * 264];
    __shared__ __align__(16) short AGs[32 * 264];
    __shared__ __align__(16) short Bs[256 * 72];
    __shared__ float s1buf[32][2];
    __shared__ float s2buf[32][2];
    const int tid = threadIdx.x;
    const int wv = tid >> 6, l = tid & 63;
    const int lr = l & 15, lk = l >> 4;
    const int bm = blockIdx.x, b = bm >> 4, m = bm & 15;
    const int q0 = blockIdx.y * 32;
    const int wq = (wv >> 1) * 16;
    const int wd = (wv & 1) * 32;
    const int sr = tid >> 3, sc = (tid & 7) * 8;

    #pragma unroll
    for (int p = 0; p < 4; ++p) {
        const int chunk = tid + p * 256;
        const int row = chunk >> 5, cc = (chunk & 31) * 8;
        *(short8*)&Qs[row * 264 + cc] = *(const short8*)(PQ + (size_t)(b * 256 + q0 + row) * DIM + cc);
    }

    f32x4 accA[4][2];
    #pragma unroll
    for (int i = 0; i < 4; ++i)
        #pragma unroll
        for (int j = 0; j < 2; ++j) accA[i][j] = (f32x4){0.f, 0.f, 0.f, 0.f};
    for (int kt = 0; kt < DIM; kt += 64) {
        #pragma unroll
        for (int p = 0; p < 8; ++p) {
            const int row = sr + p * 32;
            *(short8*)&Bs[row * 72 + sc] = *(const short8*)(KVT + ((size_t)bm * DIM + row) * DIM + kt + sc);
        }
        __syncthreads();
        #pragma unroll
        for (int kc = 0; kc < 2; ++kc) {
            const short8 af = *(const short8*)&Qs[(wq + lr) * 264 + kt + kc * 32 + lk * 8];
            #pragma unroll
            for (int dc = 0; dc < 4; ++dc)
                #pragma unroll
                for (int ni = 0; ni < 2; ++ni) {
                    const short8 bfr = *(const short8*)&Bs[(dc * 64 + wd + ni * 16 + lr) * 72 + kc * 32 + lk * 8];
                    accA[dc][ni] = __builtin_amdgcn_mfma_f32_16x16x32_bf16(af, bfr, accA[dc][ni], 0, 0, 0);
                }
        }
        __syncthreads();
    }
    {
        const float pw0 = pw[0], pw1 = pw[1], pw2 = pw[2], pbv = pb[0];
        #pragma unroll
        for (int i = 0; i < 4; ++i) {
            const int rloc = wq + lk * 4 + i;
            const int qr = q0 + rloc;
            const int widx = qr >> 4, nidx = qr & 15;
            const float* e = emb + ((((size_t)(2 + b) * 256 + widx) * 16 + nidx) * 16 + m) * 3;
            const float pv = e[0] * pw0 + e[1] * pw1 + e[2] * pw2 + pbv;
            const int t = qr * 16 + m;
            #pragma unroll
            for (int dc = 0; dc < 4; ++dc)
                #pragma unroll
                for (int ni = 0; ni < 2; ++ni) {
                    const int d = dc * 64 + wd + ni * 16 + lr;
                    const size_t o = ((size_t)b * NTOK + t) * DIM + d;
                    AGs[rloc * 264 + d] = f2bf((accA[dc][ni][i] + pv) * bf2f(AR[o]));
                }
        }
    }
    __syncthreads();

    const int wn2 = (wv & 1) * 128;
    f32x4 accB[8];
    #pragma unroll
    for (int i = 0; i < 8; ++i) accB[i] = (f32x4){0.f, 0.f, 0.f, 0.f};
    for (int kt = 0; kt < DIM; kt += 64) {
        #pragma unroll
        for (int p = 0; p < 8; ++p) {
            const int row = sr + p * 32;
            *(short8*)&Bs[row * 72 + sc] = *(const short8*)(WLB + (size_t)row * DIM + kt + sc);
        }
        __syncthreads();
        #pragma unroll
        for (int kc = 0; kc < 2; ++kc) {
            const short8 af = *(const short8*)&AGs[(wq + lr) * 264 + kt + kc * 32 + lk * 8];
            #pragma unroll
            for (int ni = 0; ni < 8; ++ni) {
                const short8 bfr = *(const short8*)&Bs[(wn2 + ni * 16 + lr) * 72 + kc * 32 + lk * 8];
                accB[ni] = __builtin_amdgcn_mfma_f32_16x16x32_bf16(af, bfr, accB[ni], 0, 0, 0);
            }
        }
        __syncthreads();
    }
    float s1[4] = {0.f, 0.f, 0.f, 0.f}, s2[4] = {0.f, 0.f, 0.f, 0.f};
    #pragma unroll
    for (int ni = 0; ni < 8; ++ni) {
        const int col = wn2 + ni * 16 + lr;
        const float bv = bl[col];
        #pragma unroll
        for (int i = 0; i < 4; ++i) {
            const int rloc = wq + lk * 4 + i;
            const int t = (q0 + rloc) * 16 + m;
            const float z = accB[ni][i] + bv + bf2f(HB[((size_t)b * NTOK + t) * DIM + col]);
            accB[ni][i] = z;
            s1[i] += z; s2[i] += z * z;
        }
    }
    #pragma unroll
    for (int o = 1; o < 16; o <<= 1) {
        #pragma unroll
        for (int i = 0; i < 4; ++i) {
            s1[i] += __shfl_xor(s1[i], o);
            s2[i] += __shfl_xor(s2[i], o);
        }
    }
    if (lr == 0) {
        #pragma unroll
        for (int i = 0; i < 4; ++i) {
            const int rloc = wq + lk * 4 + i;
            s1buf[rloc][wv & 1] = s1[i];
            s2buf[rloc][wv & 1] = s2[i];
        }
    }
    __syncthreads();
    float mean[4], rstd[4];
    #pragma unroll
    for (int i = 0; i < 4; ++i) {
        const int rloc = wq + lk * 4 + i;
        const float t1 = s1buf[rloc][0] + s1buf[rloc][1];
        const float t2 = s2buf[rloc][0] + s2buf[rloc][1];
        const float mm = t1 * (1.f / DIM);
        mean[i] = mm;
        rstd[i] = rsqrtf(t2 * (1.f / DIM) - mm * mm + 1e-5f);
    }
    #pragma unroll
    for (int ni = 0; ni < 8; ++ni) {
        const int col = wn2 + ni * 16 + lr;
        const float gv = G[col], bv2 = Bt[col];
        #pragma unroll
        for (int i = 0; i < 4; ++i) {
            const int rloc = wq + lk * 4 + i;
            const int t = (q0 + rloc) * 16 + m;
            Y[((size_t)b * NTOK + t) * DIM + col] = (accB[ni][i] - mean[i]) * rstd[i] * gv + bv2;
        }
    }
}

extern "C" void kernel_launch(void* const* d_in, const int* in_sizes, int n_in,
                              void* d_out, int out_size, void* d_ws, size_t ws_size,
                              hipStream_t stream) {
    const float* x   = (const float*)d_in[0];
    const float* emb = (const float*)d_in[1];
    const float* Wa  = (const float*)d_in[2];
    const float* ba  = (const float*)d_in[3];
    const float* lng = (const float*)d_in[4];
    const float* lnb = (const float*)d_in[5];
    const float* Wc  = (const float*)d_in[6];
    const float* bc  = (const float*)d_in[7];
    const float* Wq  = (const float*)d_in[8];
    const float* bq  = (const float*)d_in[9];
    const float* Wk  = (const float*)d_in[10];
    const float* bk  = (const float*)d_in[11];
    const float* pw  = (const float*)d_in[12];
    const float* pb  = (const float*)d_in[13];
    const float* Wl  = (const float*)d_in[14];
    const float* bl  = (const float*)d_in[15];
    const float* ng  = (const float*)d_in[16];
    const float* nb  = (const float*)d_in[17];

    char* ws = (char*)d_ws;
    const size_t MB = 1024 * 1024;
    short* h_bf   = (short*)(ws + 0 * MB);    // 4 MB
    short* phik   = (short*)(ws + 4 * MB);    // 4 MB
    short* phiq   = (short*)(ws + 8 * MB);    // 256 KB
    short* kvT    = (short*)(ws + 9 * MB);    // 4 MB  [9,13)
    short* act_bf = (short*)(ws + 13 * MB);   // 4 MB  [13,17)
    short* Wk_bf  = (short*)(ws + 17 * MB);             // 128 KB
    short* Wq_bf  = (short*)(ws + 17 * MB + 128 * 1024);
    short* Wl_bf  = (short*)(ws + 17 * MB + 256 * 1024);

    fused_dual<<<dim3(80, 4, 2), dim3(256), 0, stream>>>(x, Wa, ba, act_bf,
                                                         Wc, bc, h_bf, lng, lnb,
                                                         Wk, Wk_bf, Wq, Wq_bf);
    gemm_kq<<<dim3(68, 4), dim3(256), 0, stream>>>(h_bf, Wk_bf, bk, phik, Wq_bf, bq, phiq);
    kv_mfma<<<dim3(40, 4, 4), dim3(256), 0, stream>>>(h_bf, phik, kvT, Wl, Wl_bf);
    attlin<<<dim3(32, 8), dim3(256), 0, stream>>>(phiq, kvT, emb, pw, pb, act_bf, Wl_bf, bl,
                                                  h_bf, ng, nb, (float*)d_out);
}

// Round 16
// 53.864 us; speedup vs baseline: 1.2266x; 1.0494x over previous
//
#include <hip/hip_runtime.h>

// MSMLTransformerLayer — R15 base (56.5 µs) + double-buffered LDS with
// register prefetch in fused_dual / gemm_kq (1 barrier per K-step, next-step
// global loads issued under current MFMA). kv_mfma/attlin byte-identical.

#define DIM 256
#define NTOK 4096

typedef __attribute__((ext_vector_type(8))) short short8;
typedef __attribute__((ext_vector_type(4))) short short4v;
typedef __attribute__((ext_vector_type(4))) float f32x4;

__device__ __forceinline__ float silu_f(float z) { return z / (1.f + __expf(-z)); }
__device__ __forceinline__ float elu2_f(float z) { return z > 0.f ? z + 2.f : __expf(z) + 1.f; }

__device__ __forceinline__ short f2bf(float f) {
    union { float f; unsigned u; } v; v.f = f;
    unsigned r = v.u + 0x7fffu + ((v.u >> 16) & 1u);
    return (short)(r >> 16);
}
__device__ __forceinline__ float bf2f(short s) {
    union { unsigned u; float f; } v; v.u = ((unsigned)(unsigned short)s) << 16;
    return v.f;
}
__device__ __forceinline__ short8 cvt8(const float* src) {
    const float4 a = *(const float4*)src;
    const float4 c = *(const float4*)(src + 4);
    short8 s;
    s[0] = f2bf(a.x); s[1] = f2bf(a.y); s[2] = f2bf(a.z); s[3] = f2bf(a.w);
    s[4] = f2bf(c.x); s[5] = f2bf(c.y); s[6] = f2bf(c.z); s[7] = f2bf(c.w);
    return s;
}
__device__ __forceinline__ void cast_chunk(const float* __restrict__ src, short* __restrict__ dst,
                                           int chunk, int tid) {
    const int base = chunk * 8192 + tid * 32;
    #pragma unroll
    for (int j = 0; j < 4; ++j)
        *(short8*)(dst + base + j * 8) = cvt8(src + base + j * 8);
}

// ---------------- fused dual GEMM (silu), double-buffered ---------------------
// Block tile 128x64, grid (80,4,2): x<64 GEMM; x in [64,80) cast (y==0,z==0).
// z=0: act = silu(x@Wa^T+ba); z=1: h = silu(LN(x)@Wc^T+bc), LN in-kernel.
__global__ __launch_bounds__(256) void fused_dual(
        const float* __restrict__ XF,
        const float* __restrict__ W0f, const float* __restrict__ b0, short* __restrict__ Y0,
        const float* __restrict__ W1f, const float* __restrict__ b1, short* __restrict__ Y1,
        const float* __restrict__ G, const float* __restrict__ Bt,
        const float* __restrict__ Wkf, short* __restrict__ WKB,
        const float* __restrict__ Wqf, short* __restrict__ WQB) {
    const int tid = threadIdx.x;
    if (blockIdx.x >= 64) {
        if (blockIdx.y == 0 && blockIdx.z == 0) {
            const int which = blockIdx.x - 64;
            if (which < 8) cast_chunk(Wkf, WKB, which, tid);
            else cast_chunk(Wqf, WQB, which - 8, tid);
        }
        return;
    }
    __shared__ __align__(16) short Xs[2][128 * 72];
    __shared__ __align__(16) short Ws[2][64 * 72];
    __shared__ float stats[128][2];
    const int zz = blockIdx.z;
    const float* Wf = zz ? W1f : W0f;
    const float* bias = zz ? b1 : b0;
    short* Y = zz ? Y1 : Y0;
    const int wv = tid >> 6, l = tid & 63;
    const int lr = l & 15, lk = l >> 4;
    const int r0 = blockIdx.x * 128, c0 = blockIdx.y * 64;
    const int wm = (wv >> 1) * 64, wn = (wv & 1) * 32;
    const int sr = tid >> 3, sc = (tid & 7) * 8;

    if (zz) {  // pass 1: LN stats for rows r0..r0+127 (2 threads per row)
        const int prow = tid >> 1, phalf = tid & 1;
        const float* src = XF + (size_t)(r0 + prow) * DIM + phalf * 128;
        float a1 = 0.f, a2 = 0.f;
        #pragma unroll 8
        for (int j = 0; j < 32; ++j) {
            const float4 v = *(const float4*)(src + j * 4);
            a1 += v.x + v.y + v.z + v.w;
            a2 += v.x * v.x + v.y * v.y + v.z * v.z + v.w * v.w;
        }
        a1 += __shfl_xor(a1, 1);
        a2 += __shfl_xor(a2, 1);
        if (!phalf) {
            const float mm = a1 * (1.f / DIM);
            stats[prow][0] = mm;
            stats[prow][1] = rsqrtf(a2 * (1.f / DIM) - mm * mm + 1e-5f);
        }
        __syncthreads();
    }

    f32x4 acc[4][2];
    #pragma unroll
    for (int i = 0; i < 4; ++i)
        #pragma unroll
        for (int j = 0; j < 2; ++j) acc[i][j] = (f32x4){0.f, 0.f, 0.f, 0.f};

    // prefetch registers: X 4 rows x 8 f32, W 2 rows x 8 f32
    float4 xa[4][2], wa[2][2];
    #pragma unroll
    for (int p = 0; p < 4; ++p) {
        const float* src = XF + (size_t)(r0 + sr + p * 32) * DIM + sc;
        xa[p][0] = *(const float4*)src;
        xa[p][1] = *(const float4*)(src + 4);
    }
    #pragma unroll
    for (int p = 0; p < 2; ++p) {
        const float* src = Wf + (size_t)(c0 + sr + p * 32) * DIM + sc;
        wa[p][0] = *(const float4*)src;
        wa[p][1] = *(const float4*)(src + 4);
    }

    int buf = 0;
    for (int s = 0; s < 4; ++s) {
        const int kt = s * 64;
        // ---- write prefetched regs -> LDS[buf] ----
        if (zz) {
            const float4 g1 = *(const float4*)(G + kt + sc);
            const float4 g2 = *(const float4*)(G + kt + sc + 4);
            const float4 t1 = *(const float4*)(Bt + kt + sc);
            const float4 t2 = *(const float4*)(Bt + kt + sc + 4);
            const float gv[8] = {g1.x, g1.y, g1.z, g1.w, g2.x, g2.y, g2.z, g2.w};
            const float bv[8] = {t1.x, t1.y, t1.z, t1.w, t2.x, t2.y, t2.z, t2.w};
            #pragma unroll
            for (int p = 0; p < 4; ++p) {
                const int row = sr + p * 32;
                const float mm = stats[row][0], rs = stats[row][1];
                const float v[8] = {xa[p][0].x, xa[p][0].y, xa[p][0].z, xa[p][0].w,
                                    xa[p][1].x, xa[p][1].y, xa[p][1].z, xa[p][1].w};
                short8 sS;
                #pragma unroll
                for (int j = 0; j < 8; ++j) sS[j] = f2bf((v[j] - mm) * rs * gv[j] + bv[j]);
                *(short8*)&Xs[buf][row * 72 + sc] = sS;
            }
        } else {
            #pragma unroll
            for (int p = 0; p < 4; ++p) {
                const int row = sr + p * 32;
                const float v[8] = {xa[p][0].x, xa[p][0].y, xa[p][0].z, xa[p][0].w,
                                    xa[p][1].x, xa[p][1].y, xa[p][1].z, xa[p][1].w};
                short8 sS;
                #pragma unroll
                for (int j = 0; j < 8; ++j) sS[j] = f2bf(v[j]);
                *(short8*)&Xs[buf][row * 72 + sc] = sS;
            }
        }
        #pragma unroll
        for (int p = 0; p < 2; ++p) {
            const int row = sr + p * 32;
            const float v[8] = {wa[p][0].x, wa[p][0].y, wa[p][0].z, wa[p][0].w,
                                wa[p][1].x, wa[p][1].y, wa[p][1].z, wa[p][1].w};
            short8 sS;
            #pragma unroll
            for (int j = 0; j < 8; ++j) sS[j] = f2bf(v[j]);
            *(short8*)&Ws[buf][row * 72 + sc] = sS;
        }
        __syncthreads();
        // ---- issue next-step global loads (latency hides under MFMA) ----
        if (s < 3) {
            const int ktn = kt + 64;
            #pragma unroll
            for (int p = 0; p < 4; ++p) {
                const float* src = XF + (size_t)(r0 + sr + p * 32) * DIM + ktn + sc;
                xa[p][0] = *(const float4*)src;
                xa[p][1] = *(const float4*)(src + 4);
            }
            #pragma unroll
            for (int p = 0; p < 2; ++p) {
                const float* src = Wf + (size_t)(c0 + sr + p * 32) * DIM + ktn + sc;
                wa[p][0] = *(const float4*)src;
                wa[p][1] = *(const float4*)(src + 4);
            }
        }
        // ---- MFMA from LDS[buf] ----
        #pragma unroll
        for (int kc = 0; kc < 2; ++kc) {
            short8 af[4], bfr[2];
            #pragma unroll
            for (int mi = 0; mi < 4; ++mi)
                af[mi] = *(const short8*)&Xs[buf][(wm + mi * 16 + lr) * 72 + kc * 32 + lk * 8];
            #pragma unroll
            for (int ni = 0; ni < 2; ++ni)
                bfr[ni] = *(const short8*)&Ws[buf][(wn + ni * 16 + lr) * 72 + kc * 32 + lk * 8];
            #pragma unroll
            for (int mi = 0; mi < 4; ++mi)
                #pragma unroll
                for (int ni = 0; ni < 2; ++ni)
                    acc[mi][ni] = __builtin_amdgcn_mfma_f32_16x16x32_bf16(af[mi], bfr[ni], acc[mi][ni], 0, 0, 0);
        }
        buf ^= 1;
    }
    #pragma unroll
    for (int mi = 0; mi < 4; ++mi)
        #pragma unroll
        for (int ni = 0; ni < 2; ++ni) {
            const int c = c0 + wn + ni * 16 + lr;
            const float bv2 = bias[c];
            #pragma unroll
            for (int i = 0; i < 4; ++i) {
                const int r = r0 + wm + mi * 16 + lk * 4 + i;
                Y[(size_t)r * DIM + c] = f2bf(silu_f(acc[mi][ni][i] + bv2));
            }
        }
}

// ---------------- k/q GEMM (elu+2), double-buffered, bf16 weights ------------
__global__ __launch_bounds__(256) void gemm_kq(
        const short* __restrict__ H, const short* __restrict__ WKB, const float* __restrict__ bk, short* __restrict__ PK,
        const short* __restrict__ WQB, const float* __restrict__ bq, short* __restrict__ PQ) {
    __shared__ __align__(16) short Xs[2][128 * 72];
    __shared__ __align__(16) short Ws[2][64 * 72];
    const int bx = blockIdx.x;
    const bool isq = bx >= 64;
    const short* W = isq ? WQB : WKB;
    const float* bias = isq ? bq : bk;
    short* Y = isq ? PQ : PK;
    const int r0 = (isq ? bx - 64 : bx) * 128;
    const int c0 = blockIdx.y * 64;
    const int tid = threadIdx.x;
    const int wv = tid >> 6, l = tid & 63;
    const int lr = l & 15, lk = l >> 4;
    const int wm = (wv >> 1) * 64, wn = (wv & 1) * 32;
    const int sr = tid >> 3, sc = (tid & 7) * 8;

    int growA[4];
    #pragma unroll
    for (int p = 0; p < 4; ++p) {
        int grow = r0 + sr + p * 32;
        if (isq) grow = ((grow >> 8) << 12) + (grow & 255);
        growA[p] = grow;
    }

    f32x4 acc[4][2];
    #pragma unroll
    for (int i = 0; i < 4; ++i)
        #pragma unroll
        for (int j = 0; j < 2; ++j) acc[i][j] = (f32x4){0.f, 0.f, 0.f, 0.f};

    short8 xa[4], wa[2];
    #pragma unroll
    for (int p = 0; p < 4; ++p)
        xa[p] = *(const short8*)(H + (size_t)growA[p] * DIM + sc);
    #pragma unroll
    for (int p = 0; p < 2; ++p)
        wa[p] = *(const short8*)(W + (size_t)(c0 + sr + p * 32) * DIM + sc);

    int buf = 0;
    for (int s = 0; s < 4; ++s) {
        #pragma unroll
        for (int p = 0; p < 4; ++p)
            *(short8*)&Xs[buf][(sr + p * 32) * 72 + sc] = xa[p];
        #pragma unroll
        for (int p = 0; p < 2; ++p)
            *(short8*)&Ws[buf][(sr + p * 32) * 72 + sc] = wa[p];
        __syncthreads();
        if (s < 3) {
            const int ktn = (s + 1) * 64;
            #pragma unroll
            for (int p = 0; p < 4; ++p)
                xa[p] = *(const short8*)(H + (size_t)growA[p] * DIM + ktn + sc);
            #pragma unroll
            for (int p = 0; p < 2; ++p)
                wa[p] = *(const short8*)(W + (size_t)(c0 + sr + p * 32) * DIM + ktn + sc);
        }
        #pragma unroll
        for (int kc = 0; kc < 2; ++kc) {
            short8 af[4], bfr[2];
            #pragma unroll
            for (int mi = 0; mi < 4; ++mi)
                af[mi] = *(const short8*)&Xs[buf][(wm + mi * 16 + lr) * 72 + kc * 32 + lk * 8];
            #pragma unroll
            for (int ni = 0; ni < 2; ++ni)
                bfr[ni] = *(const short8*)&Ws[buf][(wn + ni * 16 + lr) * 72 + kc * 32 + lk * 8];
            #pragma unroll
            for (int mi = 0; mi < 4; ++mi)
                #pragma unroll
                for (int ni = 0; ni < 2; ++ni)
                    acc[mi][ni] = __builtin_amdgcn_mfma_f32_16x16x32_bf16(af[mi], bfr[ni], acc[mi][ni], 0, 0, 0);
        }
        buf ^= 1;
    }
    #pragma unroll
    for (int mi = 0; mi < 4; ++mi)
        #pragma unroll
        for (int ni = 0; ni < 2; ++ni) {
            const int c = c0 + wn + ni * 16 + lr;
            const float bv = bias[c];
            #pragma unroll
            for (int i = 0; i < 4; ++i) {
                const int r = r0 + wm + mi * 16 + lk * 4 + i;
                Y[(size_t)r * DIM + c] = f2bf(elu2_f(acc[mi][ni][i] + bv));
            }
        }
}

// ---------------- KV + Wl cast side-blocks (R15-proven) ----------------------
__global__ __launch_bounds__(256) void kv_mfma(const short* __restrict__ HB, const short* __restrict__ PK,
                                               short* __restrict__ KVT,
                                               const float* __restrict__ Wlf, short* __restrict__ WLB) {
    const int tid = threadIdx.x;
    if (blockIdx.x >= 32) {
        if (blockIdx.y == 0 && blockIdx.z == 0)
            cast_chunk(Wlf, WLB, blockIdx.x - 32, tid);
        return;
    }
    __shared__ __align__(16) short Hs[64 * 68];
    __shared__ __align__(16) short Ps[64 * 68];
    const int bm = blockIdx.x, b = bm >> 4, m = bm & 15;
    const int d0 = blockIdx.y * 64, c0 = blockIdx.z * 64;
    const int wv = tid >> 6, l = tid & 63;
    const int lr = l & 15, lk = l >> 4;
    const int wd = (wv >> 1) * 32, wc = (wv & 1) * 32;
    f32x4 acc[2][2];
    #pragma unroll
    for (int i = 0; i < 2; ++i)
        #pragma unroll
        for (int j = 0; j < 2; ++j) acc[i][j] = (f32x4){0.f, 0.f, 0.f, 0.f};
    const size_t hbase = (size_t)b * NTOK * DIM;
    const int sr = tid >> 3, sc = (tid & 7) * 8;
    for (int kt = 0; kt < 256; kt += 64) {
        #pragma unroll
        for (int p = 0; p < 2; ++p) {
            const int w = sr + p * 32;
            const size_t gg = hbase + (size_t)((kt + w) * 16 + m) * DIM;
            short8 hv = *(const short8*)(HB + gg + d0 + sc);
            short8 pv = *(const short8*)(PK + gg + c0 + sc);
            *(short4v*)&Hs[w * 68 + sc]     = __builtin_shufflevector(hv, hv, 0, 1, 2, 3);
            *(short4v*)&Hs[w * 68 + sc + 4] = __builtin_shufflevector(hv, hv, 4, 5, 6, 7);
            *(short4v*)&Ps[w * 68 + sc]     = __builtin_shufflevector(pv, pv, 0, 1, 2, 3);
            *(short4v*)&Ps[w * 68 + sc + 4] = __builtin_shufflevector(pv, pv, 4, 5, 6, 7);
        }
        __syncthreads();
        #pragma unroll
        for (int kc = 0; kc < 2; ++kc) {
            const int kb = kc * 32 + lk * 8;
            short8 af[2], bfr[2];
            #pragma unroll
            for (int di = 0; di < 2; ++di)
                #pragma unroll
                for (int i = 0; i < 8; ++i)
                    af[di][i] = Hs[(kb + i) * 68 + wd + di * 16 + lr];
            #pragma unroll
            for (int ci = 0; ci < 2; ++ci)
                #pragma unroll
                for (int i = 0; i < 8; ++i)
                    bfr[ci][i] = Ps[(kb + i) * 68 + wc + ci * 16 + lr];
            #pragma unroll
            for (int di = 0; di < 2; ++di)
                #pragma unroll
                for (int ci = 0; ci < 2; ++ci)
                    acc[di][ci] = __builtin_amdgcn_mfma_f32_16x16x32_bf16(af[di], bfr[ci], acc[di][ci], 0, 0, 0);
        }
        __syncthreads();
    }
    #pragma unroll
    for (int di = 0; di < 2; ++di)
        #pragma unroll
        for (int ci = 0; ci < 2; ++ci)
            #pragma unroll
            for (int i = 0; i < 4; ++i) {
                const int d = d0 + wd + di * 16 + lk * 4 + i;
                const int c = c0 + wc + ci * 16 + lr;
                KVT[((size_t)bm * DIM + d) * DIM + c] = f2bf(acc[di][ci][i]);
            }
}

// ---------------- attlin: bf16 Wl (R15-proven) -------------------------------
__global__ __launch_bounds__(256) void attlin(
        const short* __restrict__ PQ, const short* __restrict__ KVT,
        const float* __restrict__ emb, const float* __restrict__ pw, const float* __restrict__ pb,
        const short* __restrict__ AR,
        const short* __restrict__ WLB, const float* __restrict__ bl,
        const short* __restrict__ HB, const float* __restrict__ G, const float* __restrict__ Bt,
        float* __restrict__ Y) {
    __shared__ __align__(16) short Qs[32 * 264];
    __shared__ __align__(16) short AGs[32 * 264];
    __shared__ __align__(16) short Bs[256 * 72];
    __shared__ float s1buf[32][2];
    __shared__ float s2buf[32][2];
    const int tid = threadIdx.x;
    const int wv = tid >> 6, l = tid & 63;
    const int lr = l & 15, lk = l >> 4;
    const int bm = blockIdx.x, b = bm >> 4, m = bm & 15;
    const int q0 = blockIdx.y * 32;
    const int wq = (wv >> 1) * 16;
    const int wd = (wv & 1) * 32;
    const int sr = tid >> 3, sc = (tid & 7) * 8;

    #pragma unroll
    for (int p = 0; p < 4; ++p) {
        const int chunk = tid + p * 256;
        const int row = chunk >> 5, cc = (chunk & 31) * 8;
        *(short8*)&Qs[row * 264 + cc] = *(const short8*)(PQ + (size_t)(b * 256 + q0 + row) * DIM + cc);
    }

    f32x4 accA[4][2];
    #pragma unroll
    for (int i = 0; i < 4; ++i)
        #pragma unroll
        for (int j = 0; j < 2; ++j) accA[i][j] = (f32x4){0.f, 0.f, 0.f, 0.f};
    for (int kt = 0; kt < DIM; kt += 64) {
        #pragma unroll
        for (int p = 0; p < 8; ++p) {
            const int row = sr + p * 32;
            *(short8*)&Bs[row * 72 + sc] = *(const short8*)(KVT + ((size_t)bm * DIM + row) * DIM + kt + sc);
        }
        __syncthreads();
        #pragma unroll
        for (int kc = 0; kc < 2; ++kc) {
            const short8 af = *(const short8*)&Qs[(wq + lr) * 264 + kt + kc * 32 + lk * 8];
            #pragma unroll
            for (int dc = 0; dc < 4; ++dc)
                #pragma unroll
                for (int ni = 0; ni < 2; ++ni) {
                    const short8 bfr = *(const short8*)&Bs[(dc * 64 + wd + ni * 16 + lr) * 72 + kc * 32 + lk * 8];
                    accA[dc][ni] = __builtin_amdgcn_mfma_f32_16x16x32_bf16(af, bfr, accA[dc][ni], 0, 0, 0);
                }
        }
        __syncthreads();
    }
    {
        const float pw0 = pw[0], pw1 = pw[1], pw2 = pw[2], pbv = pb[0];
        #pragma unroll
        for (int i = 0; i < 4; ++i) {
            const int rloc = wq + lk * 4 + i;
            const int qr = q0 + rloc;
            const int widx = qr >> 4, nidx = qr & 15;
            const float* e = emb + ((((size_t)(2 + b) * 256 + widx) * 16 + nidx) * 16 + m) * 3;
            const float pv = e[0] * pw0 + e[1] * pw1 + e[2] * pw2 + pbv;
            const int t = qr * 16 + m;
            #pragma unroll
            for (int dc = 0; dc < 4; ++dc)
                #pragma unroll
                for (int ni = 0; ni < 2; ++ni) {
                    const int d = dc * 64 + wd + ni * 16 + lr;
                    const size_t o = ((size_t)b * NTOK + t) * DIM + d;
                    AGs[rloc * 264 + d] = f2bf((accA[dc][ni][i] + pv) * bf2f(AR[o]));
                }
        }
    }
    __syncthreads();

    const int wn2 = (wv & 1) * 128;
    f32x4 accB[8];
    #pragma unroll
    for (int i = 0; i < 8; ++i) accB[i] = (f32x4){0.f, 0.f, 0.f, 0.f};
    for (int kt = 0; kt < DIM; kt += 64) {
        #pragma unroll
        for (int p = 0; p < 8; ++p) {
            const int row = sr + p * 32;
            *(short8*)&Bs[row * 72 + sc] = *(const short8*)(WLB + (size_t)row * DIM + kt + sc);
        }
        __syncthreads();
        #pragma unroll
        for (int kc = 0; kc < 2; ++kc) {
            const short8 af = *(const short8*)&AGs[(wq + lr) * 264 + kt + kc * 32 + lk * 8];
            #pragma unroll
            for (int ni = 0; ni < 8; ++ni) {
                const short8 bfr = *(const short8*)&Bs[(wn2 + ni * 16 + lr) * 72 + kc * 32 + lk * 8];
                accB[ni] = __builtin_amdgcn_mfma_f32_16x16x32_bf16(af, bfr, accB[ni], 0, 0, 0);
            }
        }
        __syncthreads();
    }
    float s1[4] = {0.f, 0.f, 0.f, 0.f}, s2[4] = {0.f, 0.f, 0.f, 0.f};
    #pragma unroll
    for (int ni = 0; ni < 8; ++ni) {
        const int col = wn2 + ni * 16 + lr;
        const float bv = bl[col];
        #pragma unroll
        for (int i = 0; i < 4; ++i) {
            const int rloc = wq + lk * 4 + i;
            const int t = (q0 + rloc) * 16 + m;
            const float z = accB[ni][i] + bv + bf2f(HB[((size_t)b * NTOK + t) * DIM + col]);
            accB[ni][i] = z;
            s1[i] += z; s2[i] += z * z;
        }
    }
    #pragma unroll
    for (int o = 1; o < 16; o <<= 1) {
        #pragma unroll
        for (int i = 0; i < 4; ++i) {
            s1[i] += __shfl_xor(s1[i], o);
            s2[i] += __shfl_xor(s2[i], o);
        }
    }
    if (lr == 0) {
        #pragma unroll
        for (int i = 0; i < 4; ++i) {
            const int rloc = wq + lk * 4 + i;
            s1buf[rloc][wv & 1] = s1[i];
            s2buf[rloc][wv & 1] = s2[i];
        }
    }
    __syncthreads();
    float mean[4], rstd[4];
    #pragma unroll
    for (int i = 0; i < 4; ++i) {
        const int rloc = wq + lk * 4 + i;
        const float t1 = s1buf[rloc][0] + s1buf[rloc][1];
        const float t2 = s2buf[rloc][0] + s2buf[rloc][1];
        const float mm = t1 * (1.f / DIM);
        mean[i] = mm;
        rstd[i] = rsqrtf(t2 * (1.f / DIM) - mm * mm + 1e-5f);
    }
    #pragma unroll
    for (int ni = 0; ni < 8; ++ni) {
        const int col = wn2 + ni * 16 + lr;
        const float gv = G[col], bv2 = Bt[col];
        #pragma unroll
        for (int i = 0; i < 4; ++i) {
            const int rloc = wq + lk * 4 + i;
            const int t = (q0 + rloc) * 16 + m;
            Y[((size_t)b * NTOK + t) * DIM + col] = (accB[ni][i] - mean[i]) * rstd[i] * gv + bv2;
        }
    }
}

extern "C" void kernel_launch(void* const* d_in, const int* in_sizes, int n_in,
                              void* d_out, int out_size, void* d_ws, size_t ws_size,
                              hipStream_t stream) {
    const float* x   = (const float*)d_in[0];
    const float* emb = (const float*)d_in[1];
    const float* Wa  = (const float*)d_in[2];
    const float* ba  = (const float*)d_in[3];
    const float* lng = (const float*)d_in[4];
    const float* lnb = (const float*)d_in[5];
    const float* Wc  = (const float*)d_in[6];
    const float* bc  = (const float*)d_in[7];
    const float* Wq  = (const float*)d_in[8];
    const float* bq  = (const float*)d_in[9];
    const float* Wk  = (const float*)d_in[10];
    const float* bk  = (const float*)d_in[11];
    const float* pw  = (const float*)d_in[12];
    const float* pb  = (const float*)d_in[13];
    const float* Wl  = (const float*)d_in[14];
    const float* bl  = (const float*)d_in[15];
    const float* ng  = (const float*)d_in[16];
    const float* nb  = (const float*)d_in[17];

    char* ws = (char*)d_ws;
    const size_t MB = 1024 * 1024;
    short* h_bf   = (short*)(ws + 0 * MB);    // 4 MB
    short* phik   = (short*)(ws + 4 * MB);    // 4 MB
    short* phiq   = (short*)(ws + 8 * MB);    // 256 KB
    short* kvT    = (short*)(ws + 9 * MB);    // 4 MB  [9,13)
    short* act_bf = (short*)(ws + 13 * MB);   // 4 MB  [13,17)
    short* Wk_bf  = (short*)(ws + 17 * MB);             // 128 KB
    short* Wq_bf  = (short*)(ws + 17 * MB + 128 * 1024);
    short* Wl_bf  = (short*)(ws + 17 * MB + 256 * 1024);

    fused_dual<<<dim3(80, 4, 2), dim3(256), 0, stream>>>(x, Wa, ba, act_bf,
                                                         Wc, bc, h_bf, lng, lnb,
                                                         Wk, Wk_bf, Wq, Wq_bf);
    gemm_kq<<<dim3(68, 4), dim3(256), 0, stream>>>(h_bf, Wk_bf, bk, phik, Wq_bf, bq, phiq);
    kv_mfma<<<dim3(40, 4, 4), dim3(256), 0, stream>>>(h_bf, phik, kvT, Wl, Wl_bf);
    attlin<<<dim3(32, 8), dim3(256), 0, stream>>>(phiq, kvT, emb, pw, pb, act_bf, Wl_bf, bl,
                                                  h_bf, ng, nb, (float*)d_out);
}

// Round 17
// 53.237 us; speedup vs baseline: 1.2410x; 1.0118x over previous
//
#include <hip/hip_runtime.h>

// MSMLTransformerLayer — R16 (53.9 µs) + same dbuf+prefetch lever applied to
// kv_mfma (Hs/Ps 2-buffered) and attlin (Bs 2-buffered; grid is 1 block/CU
// already so the 108 KB LDS costs no occupancy). dual/kq byte-identical R16.

#define DIM 256
#define NTOK 4096

typedef __attribute__((ext_vector_type(8))) short short8;
typedef __attribute__((ext_vector_type(4))) short short4v;
typedef __attribute__((ext_vector_type(4))) float f32x4;

__device__ __forceinline__ float silu_f(float z) { return z / (1.f + __expf(-z)); }
__device__ __forceinline__ float elu2_f(float z) { return z > 0.f ? z + 2.f : __expf(z) + 1.f; }

__device__ __forceinline__ short f2bf(float f) {
    union { float f; unsigned u; } v; v.f = f;
    unsigned r = v.u + 0x7fffu + ((v.u >> 16) & 1u);
    return (short)(r >> 16);
}
__device__ __forceinline__ float bf2f(short s) {
    union { unsigned u; float f; } v; v.u = ((unsigned)(unsigned short)s) << 16;
    return v.f;
}
__device__ __forceinline__ short8 cvt8(const float* src) {
    const float4 a = *(const float4*)src;
    const float4 c = *(const float4*)(src + 4);
    short8 s;
    s[0] = f2bf(a.x); s[1] = f2bf(a.y); s[2] = f2bf(a.z); s[3] = f2bf(a.w);
    s[4] = f2bf(c.x); s[5] = f2bf(c.y); s[6] = f2bf(c.z); s[7] = f2bf(c.w);
    return s;
}
__device__ __forceinline__ void cast_chunk(const float* __restrict__ src, short* __restrict__ dst,
                                           int chunk, int tid) {
    const int base = chunk * 8192 + tid * 32;
    #pragma unroll
    for (int j = 0; j < 4; ++j)
        *(short8*)(dst + base + j * 8) = cvt8(src + base + j * 8);
}

// ---------------- fused dual GEMM (silu), double-buffered (R16) --------------
__global__ __launch_bounds__(256) void fused_dual(
        const float* __restrict__ XF,
        const float* __restrict__ W0f, const float* __restrict__ b0, short* __restrict__ Y0,
        const float* __restrict__ W1f, const float* __restrict__ b1, short* __restrict__ Y1,
        const float* __restrict__ G, const float* __restrict__ Bt,
        const float* __restrict__ Wkf, short* __restrict__ WKB,
        const float* __restrict__ Wqf, short* __restrict__ WQB) {
    const int tid = threadIdx.x;
    if (blockIdx.x >= 64) {
        if (blockIdx.y == 0 && blockIdx.z == 0) {
            const int which = blockIdx.x - 64;
            if (which < 8) cast_chunk(Wkf, WKB, which, tid);
            else cast_chunk(Wqf, WQB, which - 8, tid);
        }
        return;
    }
    __shared__ __align__(16) short Xs[2][128 * 72];
    __shared__ __align__(16) short Ws[2][64 * 72];
    __shared__ float stats[128][2];
    const int zz = blockIdx.z;
    const float* Wf = zz ? W1f : W0f;
    const float* bias = zz ? b1 : b0;
    short* Y = zz ? Y1 : Y0;
    const int wv = tid >> 6, l = tid & 63;
    const int lr = l & 15, lk = l >> 4;
    const int r0 = blockIdx.x * 128, c0 = blockIdx.y * 64;
    const int wm = (wv >> 1) * 64, wn = (wv & 1) * 32;
    const int sr = tid >> 3, sc = (tid & 7) * 8;

    if (zz) {
        const int prow = tid >> 1, phalf = tid & 1;
        const float* src = XF + (size_t)(r0 + prow) * DIM + phalf * 128;
        float a1 = 0.f, a2 = 0.f;
        #pragma unroll 8
        for (int j = 0; j < 32; ++j) {
            const float4 v = *(const float4*)(src + j * 4);
            a1 += v.x + v.y + v.z + v.w;
            a2 += v.x * v.x + v.y * v.y + v.z * v.z + v.w * v.w;
        }
        a1 += __shfl_xor(a1, 1);
        a2 += __shfl_xor(a2, 1);
        if (!phalf) {
            const float mm = a1 * (1.f / DIM);
            stats[prow][0] = mm;
            stats[prow][1] = rsqrtf(a2 * (1.f / DIM) - mm * mm + 1e-5f);
        }
        __syncthreads();
    }

    f32x4 acc[4][2];
    #pragma unroll
    for (int i = 0; i < 4; ++i)
        #pragma unroll
        for (int j = 0; j < 2; ++j) acc[i][j] = (f32x4){0.f, 0.f, 0.f, 0.f};

    float4 xa[4][2], wa[2][2];
    #pragma unroll
    for (int p = 0; p < 4; ++p) {
        const float* src = XF + (size_t)(r0 + sr + p * 32) * DIM + sc;
        xa[p][0] = *(const float4*)src;
        xa[p][1] = *(const float4*)(src + 4);
    }
    #pragma unroll
    for (int p = 0; p < 2; ++p) {
        const float* src = Wf + (size_t)(c0 + sr + p * 32) * DIM + sc;
        wa[p][0] = *(const float4*)src;
        wa[p][1] = *(const float4*)(src + 4);
    }

    int buf = 0;
    for (int s = 0; s < 4; ++s) {
        const int kt = s * 64;
        if (zz) {
            const float4 g1 = *(const float4*)(G + kt + sc);
            const float4 g2 = *(const float4*)(G + kt + sc + 4);
            const float4 t1 = *(const float4*)(Bt + kt + sc);
            const float4 t2 = *(const float4*)(Bt + kt + sc + 4);
            const float gv[8] = {g1.x, g1.y, g1.z, g1.w, g2.x, g2.y, g2.z, g2.w};
            const float bv[8] = {t1.x, t1.y, t1.z, t1.w, t2.x, t2.y, t2.z, t2.w};
            #pragma unroll
            for (int p = 0; p < 4; ++p) {
                const int row = sr + p * 32;
                const float mm = stats[row][0], rs = stats[row][1];
                const float v[8] = {xa[p][0].x, xa[p][0].y, xa[p][0].z, xa[p][0].w,
                                    xa[p][1].x, xa[p][1].y, xa[p][1].z, xa[p][1].w};
                short8 sS;
                #pragma unroll
                for (int j = 0; j < 8; ++j) sS[j] = f2bf((v[j] - mm) * rs * gv[j] + bv[j]);
                *(short8*)&Xs[buf][row * 72 + sc] = sS;
            }
        } else {
            #pragma unroll
            for (int p = 0; p < 4; ++p) {
                const int row = sr + p * 32;
                const float v[8] = {xa[p][0].x, xa[p][0].y, xa[p][0].z, xa[p][0].w,
                                    xa[p][1].x, xa[p][1].y, xa[p][1].z, xa[p][1].w};
                short8 sS;
                #pragma unroll
                for (int j = 0; j < 8; ++j) sS[j] = f2bf(v[j]);
                *(short8*)&Xs[buf][row * 72 + sc] = sS;
            }
        }
        #pragma unroll
        for (int p = 0; p < 2; ++p) {
            const int row = sr + p * 32;
            const float v[8] = {wa[p][0].x, wa[p][0].y, wa[p][0].z, wa[p][0].w,
                                wa[p][1].x, wa[p][1].y, wa[p][1].z, wa[p][1].w};
            short8 sS;
            #pragma unroll
            for (int j = 0; j < 8; ++j) sS[j] = f2bf(v[j]);
            *(short8*)&Ws[buf][row * 72 + sc] = sS;
        }
        __syncthreads();
        if (s < 3) {
            const int ktn = kt + 64;
            #pragma unroll
            for (int p = 0; p < 4; ++p) {
                const float* src = XF + (size_t)(r0 + sr + p * 32) * DIM + ktn + sc;
                xa[p][0] = *(const float4*)src;
                xa[p][1] = *(const float4*)(src + 4);
            }
            #pragma unroll
            for (int p = 0; p < 2; ++p) {
                const float* src = Wf + (size_t)(c0 + sr + p * 32) * DIM + ktn + sc;
                wa[p][0] = *(const float4*)src;
                wa[p][1] = *(const float4*)(src + 4);
            }
        }
        #pragma unroll
        for (int kc = 0; kc < 2; ++kc) {
            short8 af[4], bfr[2];
            #pragma unroll
            for (int mi = 0; mi < 4; ++mi)
                af[mi] = *(const short8*)&Xs[buf][(wm + mi * 16 + lr) * 72 + kc * 32 + lk * 8];
            #pragma unroll
            for (int ni = 0; ni < 2; ++ni)
                bfr[ni] = *(const short8*)&Ws[buf][(wn + ni * 16 + lr) * 72 + kc * 32 + lk * 8];
            #pragma unroll
            for (int mi = 0; mi < 4; ++mi)
                #pragma unroll
                for (int ni = 0; ni < 2; ++ni)
                    acc[mi][ni] = __builtin_amdgcn_mfma_f32_16x16x32_bf16(af[mi], bfr[ni], acc[mi][ni], 0, 0, 0);
        }
        buf ^= 1;
    }
    #pragma unroll
    for (int mi = 0; mi < 4; ++mi)
        #pragma unroll
        for (int ni = 0; ni < 2; ++ni) {
            const int c = c0 + wn + ni * 16 + lr;
            const float bv2 = bias[c];
            #pragma unroll
            for (int i = 0; i < 4; ++i) {
                const int r = r0 + wm + mi * 16 + lk * 4 + i;
                Y[(size_t)r * DIM + c] = f2bf(silu_f(acc[mi][ni][i] + bv2));
            }
        }
}

// ---------------- k/q GEMM (elu+2), double-buffered (R16) --------------------
__global__ __launch_bounds__(256) void gemm_kq(
        const short* __restrict__ H, const short* __restrict__ WKB, const float* __restrict__ bk, short* __restrict__ PK,
        const short* __restrict__ WQB, const float* __restrict__ bq, short* __restrict__ PQ) {
    __shared__ __align__(16) short Xs[2][128 * 72];
    __shared__ __align__(16) short Ws[2][64 * 72];
    const int bx = blockIdx.x;
    const bool isq = bx >= 64;
    const short* W = isq ? WQB : WKB;
    const float* bias = isq ? bq : bk;
    short* Y = isq ? PQ : PK;
    const int r0 = (isq ? bx - 64 : bx) * 128;
    const int c0 = blockIdx.y * 64;
    const int tid = threadIdx.x;
    const int wv = tid >> 6, l = tid & 63;
    const int lr = l & 15, lk = l >> 4;
    const int wm = (wv >> 1) * 64, wn = (wv & 1) * 32;
    const int sr = tid >> 3, sc = (tid & 7) * 8;

    int growA[4];
    #pragma unroll
    for (int p = 0; p < 4; ++p) {
        int grow = r0 + sr + p * 32;
        if (isq) grow = ((grow >> 8) << 12) + (grow & 255);
        growA[p] = grow;
    }

    f32x4 acc[4][2];
    #pragma unroll
    for (int i = 0; i < 4; ++i)
        #pragma unroll
        for (int j = 0; j < 2; ++j) acc[i][j] = (f32x4){0.f, 0.f, 0.f, 0.f};

    short8 xa[4], wa[2];
    #pragma unroll
    for (int p = 0; p < 4; ++p)
        xa[p] = *(const short8*)(H + (size_t)growA[p] * DIM + sc);
    #pragma unroll
    for (int p = 0; p < 2; ++p)
        wa[p] = *(const short8*)(W + (size_t)(c0 + sr + p * 32) * DIM + sc);

    int buf = 0;
    for (int s = 0; s < 4; ++s) {
        #pragma unroll
        for (int p = 0; p < 4; ++p)
            *(short8*)&Xs[buf][(sr + p * 32) * 72 + sc] = xa[p];
        #pragma unroll
        for (int p = 0; p < 2; ++p)
            *(short8*)&Ws[buf][(sr + p * 32) * 72 + sc] = wa[p];
        __syncthreads();
        if (s < 3) {
            const int ktn = (s + 1) * 64;
            #pragma unroll
            for (int p = 0; p < 4; ++p)
                xa[p] = *(const short8*)(H + (size_t)growA[p] * DIM + ktn + sc);
            #pragma unroll
            for (int p = 0; p < 2; ++p)
                wa[p] = *(const short8*)(W + (size_t)(c0 + sr + p * 32) * DIM + ktn + sc);
        }
        #pragma unroll
        for (int kc = 0; kc < 2; ++kc) {
            short8 af[4], bfr[2];
            #pragma unroll
            for (int mi = 0; mi < 4; ++mi)
                af[mi] = *(const short8*)&Xs[buf][(wm + mi * 16 + lr) * 72 + kc * 32 + lk * 8];
            #pragma unroll
            for (int ni = 0; ni < 2; ++ni)
                bfr[ni] = *(const short8*)&Ws[buf][(wn + ni * 16 + lr) * 72 + kc * 32 + lk * 8];
            #pragma unroll
            for (int mi = 0; mi < 4; ++mi)
                #pragma unroll
                for (int ni = 0; ni < 2; ++ni)
                    acc[mi][ni] = __builtin_amdgcn_mfma_f32_16x16x32_bf16(af[mi], bfr[ni], acc[mi][ni], 0, 0, 0);
        }
        buf ^= 1;
    }
    #pragma unroll
    for (int mi = 0; mi < 4; ++mi)
        #pragma unroll
        for (int ni = 0; ni < 2; ++ni) {
            const int c = c0 + wn + ni * 16 + lr;
            const float bv = bias[c];
            #pragma unroll
            for (int i = 0; i < 4; ++i) {
                const int r = r0 + wm + mi * 16 + lk * 4 + i;
                Y[(size_t)r * DIM + c] = f2bf(elu2_f(acc[mi][ni][i] + bv));
            }
        }
}

// ---------------- KV double-buffered + Wl cast side-blocks -------------------
__global__ __launch_bounds__(256) void kv_mfma(const short* __restrict__ HB, const short* __restrict__ PK,
                                               short* __restrict__ KVT,
                                               const float* __restrict__ Wlf, short* __restrict__ WLB) {
    const int tid = threadIdx.x;
    if (blockIdx.x >= 32) {
        if (blockIdx.y == 0 && blockIdx.z == 0)
            cast_chunk(Wlf, WLB, blockIdx.x - 32, tid);
        return;
    }
    __shared__ __align__(16) short Hs[2][64 * 68];
    __shared__ __align__(16) short Ps[2][64 * 68];
    const int bm = blockIdx.x, b = bm >> 4, m = bm & 15;
    const int d0 = blockIdx.y * 64, c0 = blockIdx.z * 64;
    const int wv = tid >> 6, l = tid & 63;
    const int lr = l & 15, lk = l >> 4;
    const int wd = (wv >> 1) * 32, wc = (wv & 1) * 32;
    f32x4 acc[2][2];
    #pragma unroll
    for (int i = 0; i < 2; ++i)
        #pragma unroll
        for (int j = 0; j < 2; ++j) acc[i][j] = (f32x4){0.f, 0.f, 0.f, 0.f};
    const size_t hbase = (size_t)b * NTOK * DIM;
    const int sr = tid >> 3, sc = (tid & 7) * 8;

    short8 hv[2], pv[2];
    #pragma unroll
    for (int p = 0; p < 2; ++p) {
        const int w = sr + p * 32;
        const size_t gg = hbase + (size_t)(w * 16 + m) * DIM;
        hv[p] = *(const short8*)(HB + gg + d0 + sc);
        pv[p] = *(const short8*)(PK + gg + c0 + sc);
    }

    int buf = 0;
    for (int s = 0; s < 4; ++s) {
        #pragma unroll
        for (int p = 0; p < 2; ++p) {
            const int w = sr + p * 32;
            *(short4v*)&Hs[buf][w * 68 + sc]     = __builtin_shufflevector(hv[p], hv[p], 0, 1, 2, 3);
            *(short4v*)&Hs[buf][w * 68 + sc + 4] = __builtin_shufflevector(hv[p], hv[p], 4, 5, 6, 7);
            *(short4v*)&Ps[buf][w * 68 + sc]     = __builtin_shufflevector(pv[p], pv[p], 0, 1, 2, 3);
            *(short4v*)&Ps[buf][w * 68 + sc + 4] = __builtin_shufflevector(pv[p], pv[p], 4, 5, 6, 7);
        }
        __syncthreads();
        if (s < 3) {
            const int ktn = (s + 1) * 64;
            #pragma unroll
            for (int p = 0; p < 2; ++p) {
                const int w = sr + p * 32;
                const size_t gg = hbase + (size_t)((ktn + w) * 16 + m) * DIM;
                hv[p] = *(const short8*)(HB + gg + d0 + sc);
                pv[p] = *(const short8*)(PK + gg + c0 + sc);
            }
        }
        #pragma unroll
        for (int kc = 0; kc < 2; ++kc) {
            const int kb = kc * 32 + lk * 8;
            short8 af[2], bfr[2];
            #pragma unroll
            for (int di = 0; di < 2; ++di)
                #pragma unroll
                for (int i = 0; i < 8; ++i)
                    af[di][i] = Hs[buf][(kb + i) * 68 + wd + di * 16 + lr];
            #pragma unroll
            for (int ci = 0; ci < 2; ++ci)
                #pragma unroll
                for (int i = 0; i < 8; ++i)
                    bfr[ci][i] = Ps[buf][(kb + i) * 68 + wc + ci * 16 + lr];
            #pragma unroll
            for (int di = 0; di < 2; ++di)
                #pragma unroll
                for (int ci = 0; ci < 2; ++ci)
                    acc[di][ci] = __builtin_amdgcn_mfma_f32_16x16x32_bf16(af[di], bfr[ci], acc[di][ci], 0, 0, 0);
        }
        buf ^= 1;
    }
    #pragma unroll
    for (int di = 0; di < 2; ++di)
        #pragma unroll
        for (int ci = 0; ci < 2; ++ci)
            #pragma unroll
            for (int i = 0; i < 4; ++i) {
                const int d = d0 + wd + di * 16 + lk * 4 + i;
                const int c = c0 + wc + ci * 16 + lr;
                KVT[((size_t)bm * DIM + d) * DIM + c] = f2bf(acc[di][ci][i]);
            }
}

// ---------------- attlin: Bs double-buffered (1 block/CU anyway) -------------
__global__ __launch_bounds__(256) void attlin(
        const short* __restrict__ PQ, const short* __restrict__ KVT,
        const float* __restrict__ emb, const float* __restrict__ pw, const float* __restrict__ pb,
        const short* __restrict__ AR,
        const short* __restrict__ WLB, const float* __restrict__ bl,
        const short* __restrict__ HB, const float* __restrict__ G, const float* __restrict__ Bt,
        float* __restrict__ Y) {
    __shared__ __align__(16) short Qs[32 * 264];
    __shared__ __align__(16) short AGs[32 * 264];
    __shared__ __align__(16) short Bs[2][256 * 72];
    __shared__ float s1buf[32][2];
    __shared__ float s2buf[32][2];
    const int tid = threadIdx.x;
    const int wv = tid >> 6, l = tid & 63;
    const int lr = l & 15, lk = l >> 4;
    const int bm = blockIdx.x, b = bm >> 4, m = bm & 15;
    const int q0 = blockIdx.y * 32;
    const int wq = (wv >> 1) * 16;
    const int wd = (wv & 1) * 32;
    const int sr = tid >> 3, sc = (tid & 7) * 8;

    #pragma unroll
    for (int p = 0; p < 4; ++p) {
        const int chunk = tid + p * 256;
        const int row = chunk >> 5, cc = (chunk & 31) * 8;
        *(short8*)&Qs[row * 264 + cc] = *(const short8*)(PQ + (size_t)(b * 256 + q0 + row) * DIM + cc);
    }

    // ---- phase A: AG = (Qs @ kvT^T + p) * act_res, Bs dbuf ----
    f32x4 accA[4][2];
    #pragma unroll
    for (int i = 0; i < 4; ++i)
        #pragma unroll
        for (int j = 0; j < 2; ++j) accA[i][j] = (f32x4){0.f, 0.f, 0.f, 0.f};
    short8 bv8[8];
    #pragma unroll
    for (int p = 0; p < 8; ++p)
        bv8[p] = *(const short8*)(KVT + ((size_t)bm * DIM + sr + p * 32) * DIM + sc);
    int buf = 0;
    for (int s = 0; s < 4; ++s) {
        const int kt = s * 64;
        #pragma unroll
        for (int p = 0; p < 8; ++p)
            *(short8*)&Bs[buf][(sr + p * 32) * 72 + sc] = bv8[p];
        __syncthreads();
        if (s < 3) {
            const int ktn = kt + 64;
            #pragma unroll
            for (int p = 0; p < 8; ++p)
                bv8[p] = *(const short8*)(KVT + ((size_t)bm * DIM + sr + p * 32) * DIM + ktn + sc);
        }
        #pragma unroll
        for (int kc = 0; kc < 2; ++kc) {
            const short8 af = *(const short8*)&Qs[(wq + lr) * 264 + kt + kc * 32 + lk * 8];
            #pragma unroll
            for (int dc = 0; dc < 4; ++dc)
                #pragma unroll
                for (int ni = 0; ni < 2; ++ni) {
                    const short8 bfr = *(const short8*)&Bs[buf][(dc * 64 + wd + ni * 16 + lr) * 72 + kc * 32 + lk * 8];
                    accA[dc][ni] = __builtin_amdgcn_mfma_f32_16x16x32_bf16(af, bfr, accA[dc][ni], 0, 0, 0);
                }
        }
        buf ^= 1;
    }
    __syncthreads();
    {
        const float pw0 = pw[0], pw1 = pw[1], pw2 = pw[2], pbv = pb[0];
        #pragma unroll
        for (int i = 0; i < 4; ++i) {
            const int rloc = wq + lk * 4 + i;
            const int qr = q0 + rloc;
            const int widx = qr >> 4, nidx = qr & 15;
            const float* e = emb + ((((size_t)(2 + b) * 256 + widx) * 16 + nidx) * 16 + m) * 3;
            const float pv = e[0] * pw0 + e[1] * pw1 + e[2] * pw2 + pbv;
            const int t = qr * 16 + m;
            #pragma unroll
            for (int dc = 0; dc < 4; ++dc)
                #pragma unroll
                for (int ni = 0; ni < 2; ++ni) {
                    const int d = dc * 64 + wd + ni * 16 + lr;
                    const size_t o = ((size_t)b * NTOK + t) * DIM + d;
                    AGs[rloc * 264 + d] = f2bf((accA[dc][ni][i] + pv) * bf2f(AR[o]));
                }
        }
    }
    __syncthreads();

    // ---- phase B: hid = AG @ Wl^T + bl + residual; final LN. Bs dbuf ----
    const int wn2 = (wv & 1) * 128;
    f32x4 accB[8];
    #pragma unroll
    for (int i = 0; i < 8; ++i) accB[i] = (f32x4){0.f, 0.f, 0.f, 0.f};
    #pragma unroll
    for (int p = 0; p < 8; ++p)
        bv8[p] = *(const short8*)(WLB + (size_t)(sr + p * 32) * DIM + sc);
    buf = 0;
    for (int s = 0; s < 4; ++s) {
        const int kt = s * 64;
        #pragma unroll
        for (int p = 0; p < 8; ++p)
            *(short8*)&Bs[buf][(sr + p * 32) * 72 + sc] = bv8[p];
        __syncthreads();
        if (s < 3) {
            const int ktn = kt + 64;
            #pragma unroll
            for (int p = 0; p < 8; ++p)
                bv8[p] = *(const short8*)(WLB + (size_t)(sr + p * 32) * DIM + ktn + sc);
        }
        #pragma unroll
        for (int kc = 0; kc < 2; ++kc) {
            const short8 af = *(const short8*)&AGs[(wq + lr) * 264 + kt + kc * 32 + lk * 8];
            #pragma unroll
            for (int ni = 0; ni < 8; ++ni) {
                const short8 bfr = *(const short8*)&Bs[buf][(wn2 + ni * 16 + lr) * 72 + kc * 32 + lk * 8];
                accB[ni] = __builtin_amdgcn_mfma_f32_16x16x32_bf16(af, bfr, accB[ni], 0, 0, 0);
            }
        }
        buf ^= 1;
    }
    float s1[4] = {0.f, 0.f, 0.f, 0.f}, s2[4] = {0.f, 0.f, 0.f, 0.f};
    #pragma unroll
    for (int ni = 0; ni < 8; ++ni) {
        const int col = wn2 + ni * 16 + lr;
        const float bv = bl[col];
        #pragma unroll
        for (int i = 0; i < 4; ++i) {
            const int rloc = wq + lk * 4 + i;
            const int t = (q0 + rloc) * 16 + m;
            const float z = accB[ni][i] + bv + bf2f(HB[((size_t)b * NTOK + t) * DIM + col]);
            accB[ni][i] = z;
            s1[i] += z; s2[i] += z * z;
        }
    }
    #pragma unroll
    for (int o = 1; o < 16; o <<= 1) {
        #pragma unroll
        for (int i = 0; i < 4; ++i) {
            s1[i] += __shfl_xor(s1[i], o);
            s2[i] += __shfl_xor(s2[i], o);
        }
    }
    if (lr == 0) {
        #pragma unroll
        for (int i = 0; i < 4; ++i) {
            const int rloc = wq + lk * 4 + i;
            s1buf[rloc][wv & 1] = s1[i];
            s2buf[rloc][wv & 1] = s2[i];
        }
    }
    __syncthreads();
    float mean[4], rstd[4];
    #pragma unroll
    for (int i = 0; i < 4; ++i) {
        const int rloc = wq + lk * 4 + i;
        const float t1 = s1buf[rloc][0] + s1buf[rloc][1];
        const float t2 = s2buf[rloc][0] + s2buf[rloc][1];
        const float mm = t1 * (1.f / DIM);
        mean[i] = mm;
        rstd[i] = rsqrtf(t2 * (1.f / DIM) - mm * mm + 1e-5f);
    }
    #pragma unroll
    for (int ni = 0; ni < 8; ++ni) {
        const int col = wn2 + ni * 16 + lr;
        const float gv = G[col], bv2 = Bt[col];
        #pragma unroll
        for (int i = 0; i < 4; ++i) {
            const int rloc = wq + lk * 4 + i;
            const int t = (q0 + rloc) * 16 + m;
            Y[((size_t)b * NTOK + t) * DIM + col] = (accB[ni][i] - mean[i]) * rstd[i] * gv + bv2;
        }
    }
}

extern "C" void kernel_launch(void* const* d_in, const int* in_sizes, int n_in,
                              void* d_out, int out_size, void* d_ws, size_t ws_size,
                              hipStream_t stream) {
    const float* x   = (const float*)d_in[0];
    const float* emb = (const float*)d_in[1];
    const float* Wa  = (const float*)d_in[2];
    const float* ba  = (const float*)d_in[3];
    const float* lng = (const float*)d_in[4];
    const float* lnb = (const float*)d_in[5];
    const float* Wc  = (const float*)d_in[6];
    const float* bc  = (const float*)d_in[7];
    const float* Wq  = (const float*)d_in[8];
    const float* bq  = (const float*)d_in[9];
    const float* Wk  = (const float*)d_in[10];
    const float* bk  = (const float*)d_in[11];
    const float* pw  = (const float*)d_in[12];
    const float* pb  = (const float*)d_in[13];
    const float* Wl  = (const float*)d_in[14];
    const float* bl  = (const float*)d_in[15];
    const float* ng  = (const float*)d_in[16];
    const float* nb  = (const float*)d_in[17];

    char* ws = (char*)d_ws;
    const size_t MB = 1024 * 1024;
    short* h_bf   = (short*)(ws + 0 * MB);    // 4 MB
    short* phik   = (short*)(ws + 4 * MB);    // 4 MB
    short* phiq   = (short*)(ws + 8 * MB);    // 256 KB
    short* kvT    = (short*)(ws + 9 * MB);    // 4 MB  [9,13)
    short* act_bf = (short*)(ws + 13 * MB);   // 4 MB  [13,17)
    short* Wk_bf  = (short*)(ws + 17 * MB);             // 128 KB
    short* Wq_bf  = (short*)(ws + 17 * MB + 128 * 1024);
    short* Wl_bf  = (short*)(ws + 17 * MB + 256 * 1024);

    fused_dual<<<dim3(80, 4, 2), dim3(256), 0, stream>>>(x, Wa, ba, act_bf,
                                                         Wc, bc, h_bf, lng, lnb,
                                                         Wk, Wk_bf, Wq, Wq_bf);
    gemm_kq<<<dim3(68, 4), dim3(256), 0, stream>>>(h_bf, Wk_bf, bk, phik, Wq_bf, bq, phiq);
    kv_mfma<<<dim3(40, 4, 4), dim3(256), 0, stream>>>(h_bf, phik, kvT, Wl, Wl_bf);
    attlin<<<dim3(32, 8), dim3(256), 0, stream>>>(phiq, kvT, emb, pw, pb, act_bf, Wl_bf, bl,
                                                  h_bf, ng, nb, (float*)d_out);
}